// Round 5
// baseline (12021.404 us; speedup 1.0000x reference)
//
#include <hip/hip_runtime.h>
#include <hip/hip_bf16.h>
#include <math.h>

// ---------------- constants (fixed by setup_inputs) ----------------
constexpr int B   = 128;   // batch
constexpr int N1  = 32;    // agents (1 ego + 31 veh)
constexpr int HH  = 20;    // history steps (T-2)
constexpr int L   = 64;    // lanes
constexpr int PTS = 10;    // points per lane
constexpr int F   = 128;   // feature size
constexpr int LF  = 64;    // lane feature
constexpr int NH  = 8;     // heads
constexpr int HD  = 16;    // head dim
constexpr int KVN = 96;    // kv tokens = 32 agents + 64 lanes
constexpr int G4  = 512;   // 4*F lstm gates
constexpr int NP  = 6;     // num preds
constexpr int P6  = 36;    // NP*6
constexpr int LEN = 30;    // len_pred

__device__ __forceinline__ float sigmoidf(float x) { return 1.f / (1.f + expf(-x)); }
__device__ __forceinline__ float dot4(float4 a, float4 b) {
    return a.x * b.x + a.y * b.y + a.z * b.z + a.w * b.w;
}

// ---------------- one-time kernels ----------------

// lane MLP -> lane tokens (kv rows 32..95). One wave per (b,l).
// w1/b1 broadcast via LDS (pipelined), w2/to_f per-lane coalesced.
__global__ __launch_bounds__(64) void k_lane_tok(
        const float* __restrict__ lane_input,
        const float* __restrict__ w1, const float* __restrict__ b1,
        const float* __restrict__ w2, const float* __restrict__ b2,
        const float* __restrict__ to_f,
        float* __restrict__ kvbuf) {
    int bl = blockIdx.x; int b = bl / L, l = bl % L;
    int j = threadIdx.x; // 64
    __shared__ float w1s[2 * LF];
    __shared__ float b1s[LF];
    __shared__ float ml[LF];
    w1s[j] = w1[j]; w1s[LF + j] = w1[LF + j]; b1s[j] = b1[j];
    float x0[PTS], x1[PTS];
#pragma unroll
    for (int p = 0; p < PTS; ++p) {
        x0[p] = lane_input[((size_t)(b * L + l) * PTS + p) * 2 + 0]; // uniform, batched
        x1[p] = lane_input[((size_t)(b * L + l) * PTS + p) * 2 + 1];
    }
    __syncthreads();
    float mp[PTS];
#pragma unroll
    for (int p = 0; p < PTS; ++p) mp[p] = 0.f;
    for (int hh = 0; hh < LF; ++hh) {
        float w10 = w1s[hh], w11 = w1s[LF + hh], b1h = b1s[hh]; // LDS broadcast
        float wv = w2[hh * LF + j];                             // coalesced
#pragma unroll
        for (int p = 0; p < PTS; ++p) {
            float h1v = fmaxf(x0[p] * w10 + x1[p] * w11 + b1h, 0.f);
            mp[p] += h1v * wv;
        }
    }
    float b2j = b2[j];
    float m = 0.f;
#pragma unroll
    for (int p = 0; p < PTS; ++p) m += fmaxf(mp[p] + b2j, 0.f);
    ml[j] = m * (1.f / PTS);
    __syncthreads();
    float* outp = kvbuf + ((size_t)(b * KVN) + 32 + l) * F;
    float acc0 = 0.f, acc1 = 0.f;
    for (int j2 = 0; j2 < LF; ++j2) {
        float mv = ml[j2];
        acc0 += mv * to_f[j2 * F + j];
        acc1 += mv * to_f[j2 * F + 64 + j];
    }
    outp[j] = acc0; outp[64 + j] = acc1;
}

// lane K/V: project constant lane tokens once. 8 rows per block.
__global__ __launch_bounds__(256) void k_lane_kv(
        const float* __restrict__ kvbuf,
        const float* __restrict__ wk_t, const float* __restrict__ wv_t,
        float* __restrict__ kb, float* __restrict__ vb) {
    int g = blockIdx.x & 7, b = blockIdx.x >> 3;
    int n0 = 32 + g * 8;
    int tid = threadIdx.x; // 256 = 4 waves
    int w = tid >> 6, j = tid & 63;
    int r0 = (w >> 1) * 4;          // rows 0-3 or 4-7
    int c = (w & 1) * 64 + j;       // col half
    __shared__ float tok[8][F];
    for (int i = tid; i < 8 * F; i += 256) {
        int r = i >> 7, cc = i & 127;
        tok[r][cc] = kvbuf[((size_t)b * KVN + n0 + r) * F + cc];
    }
    __syncthreads();
    float ak[4] = {0, 0, 0, 0}, av[4] = {0, 0, 0, 0};
    for (int k2 = 0; k2 < F; k2 += 4) {
        float4 wkv = *(const float4*)(wk_t + (size_t)c * F + k2);
        float4 wvv = *(const float4*)(wv_t + (size_t)c * F + k2);
#pragma unroll
        for (int r = 0; r < 4; ++r) {
            float4 xv = *(const float4*)&tok[r0 + r][k2];
            ak[r] += dot4(xv, wkv); av[r] += dot4(xv, wvv);
        }
    }
#pragma unroll
    for (int r = 0; r < 4; ++r) {
        int n = n0 + r0 + r;
        kb[((size_t)b * KVN + n) * F + c] = ak[r];
        vb[((size_t)b * KVN + n) * F + c] = av[r];
    }
}

__global__ void k_hist_pos(const float* __restrict__ input,
                           const float* __restrict__ init_pos,
                           float* __restrict__ hist_pos,
                           float* __restrict__ pred_pos) {
    int idx = blockIdx.x * blockDim.x + threadIdx.x;
    if (idx >= B * N1) return;
    float px = init_pos[idx * 2], py = init_pos[idx * 2 + 1];
    int b = idx / N1, n = idx % N1;
    for (int t = 0; t < HH; ++t) {
        const float* ip = input + ((size_t)(t * B + b) * N1 + n) * 2;
        float dl = ip[0], yaw = ip[1];
        px += dl * cosf(yaw);
        py += dl * sinf(yaw);
        float* hp = hist_pos + ((size_t)(t * B + b) * N1 + n) * 2;
        hp[0] = px; hp[1] = py;
    }
#pragma unroll
    for (int p = 0; p < NP; ++p) {
        pred_pos[((size_t)idx * NP + p) * 2 + 0] = px;
        pred_pos[((size_t)idx * NP + p) * 2 + 1] = py;
    }
}

// transpose wq,wk,wv,wo (each F x F, k-major) -> (col, k) layout
__global__ void k_transpose4(const float* __restrict__ w0, const float* __restrict__ w1,
                             const float* __restrict__ w2, const float* __restrict__ w3,
                             float* __restrict__ wt) {
    int m = blockIdx.x >> 7, c = blockIdx.x & 127;
    int k = threadIdx.x; // 128
    const float* src = (m == 0) ? w0 : (m == 1) ? w1 : (m == 2) ? w2 : w3;
    wt[(size_t)m * F * F + (size_t)c * F + k] = src[(size_t)k * F + c];
}

// ---------------- per-step kernels ----------------

// Kernel A: build agent tokens + q/k/v projections. grid B*4, block 256, 8 rows/block.
// wave: (row-half, col-half); lane handles 1 col x {q,k,v} x 4 rows.
__global__ __launch_bounds__(256) void k_tok_qkv(
        const float* __restrict__ input, const float* __restrict__ hist_pos,
        const float* __restrict__ h, const float* __restrict__ pred_pos,
        const float* __restrict__ conv_w, const float* __restrict__ conv_b,
        const float* __restrict__ pos_w, const float* __restrict__ pos_b,
        const float* __restrict__ wq_t, const float* __restrict__ wk_t,
        const float* __restrict__ wv_t,
        float* __restrict__ kvbuf, float* __restrict__ qb,
        float* __restrict__ kb, float* __restrict__ vb,
        int mode, int t) {
    int g = blockIdx.x & 3, b = blockIdx.x >> 2;
    int n0 = g * 8;
    int tid = threadIdx.x;
    int w = tid >> 6, j = tid & 63;
    int r0 = (w >> 1) * 4;
    int c = (w & 1) * 64 + j;
    __shared__ float tok[8][F];
    __shared__ float mpos[8][2];
    if (mode == 1 && tid < 8) {
        const float* pp = pred_pos + ((size_t)(b * N1 + n0 + tid)) * NP * 2;
        float mx = 0.f, my = 0.f;
#pragma unroll
        for (int p = 0; p < NP; ++p) { mx += pp[p * 2]; my += pp[p * 2 + 1]; }
        mpos[tid][0] = mx * (1.f / NP); mpos[tid][1] = my * (1.f / NP);
    }
    __syncthreads();
    for (int i = tid; i < 8 * F; i += 256) {
        int r = i >> 7, cc = i & 127;
        int n = n0 + r;
        float acc;
        if (mode == 0) {
            acc = conv_b[cc];
#pragma unroll
            for (int kt = 0; kt < 3; ++kt) {
                const float* ip = input + ((size_t)((t + kt) * B + b) * N1 + n) * 2;
                acc += ip[0] * conv_w[(cc * 2 + 0) * 3 + kt] + ip[1] * conv_w[(cc * 2 + 1) * 3 + kt];
            }
            const float* hp = hist_pos + ((size_t)(t * B + b) * N1 + n) * 2;
            acc += hp[0] * pos_w[cc] + hp[1] * pos_w[F + cc] + pos_b[cc];
        } else {
            acc = h[((size_t)b * N1 + n) * F + cc]
                + mpos[r][0] * pos_w[cc] + mpos[r][1] * pos_w[F + cc] + pos_b[cc];
        }
        tok[r][cc] = acc;
        kvbuf[((size_t)b * KVN + n) * F + cc] = acc;
    }
    __syncthreads();
    float aq[4] = {0, 0, 0, 0}, ak[4] = {0, 0, 0, 0}, av[4] = {0, 0, 0, 0};
    for (int k2 = 0; k2 < F; k2 += 4) {
        float4 wqv = *(const float4*)(wq_t + (size_t)c * F + k2);
        float4 wkv = *(const float4*)(wk_t + (size_t)c * F + k2);
        float4 wvv = *(const float4*)(wv_t + (size_t)c * F + k2);
#pragma unroll
        for (int r = 0; r < 4; ++r) {
            float4 xv = *(const float4*)&tok[r0 + r][k2];
            aq[r] += dot4(xv, wqv); ak[r] += dot4(xv, wkv); av[r] += dot4(xv, wvv);
        }
    }
#pragma unroll
    for (int r = 0; r < 4; ++r) {
        int n = n0 + r0 + r;
        qb[((size_t)b * N1 + n) * F + c]  = aq[r];
        kb[((size_t)b * KVN + n) * F + c] = ak[r];
        vb[((size_t)b * KVN + n) * F + c] = av[r];
    }
}

// Kernel B1: attention, online softmax in registers. One wave per (b, 8 q-rows).
// lane = (qi, h). Mask staged in LDS (no per-iteration scalar loads).
__global__ __launch_bounds__(64) void k_attn(
        const float* __restrict__ qb, const float* __restrict__ kb,
        const float* __restrict__ vb,
        const float* __restrict__ mask_in, const float* __restrict__ lane_mask,
        float* __restrict__ ao) {
    int qg = blockIdx.x & 3, b = blockIdx.x >> 2;
    int t = threadIdx.x;
    int h = t & 7, qi = t >> 3;
    int qr = qg * 8 + qi;
    __shared__ float mk[KVN];
    for (int i = t; i < KVN; i += 64)
        mk[i] = (i < N1) ? mask_in[b * N1 + i] : lane_mask[b * L + (i - N1)];
    const float4* qp = (const float4*)(qb + ((size_t)b * N1 + qr) * F + h * HD);
    float4 q0 = qp[0], q1 = qp[1], q2 = qp[2], q3 = qp[3];
    __syncthreads();
    float m = -1e30f, l = 0.f;
    float4 o0 = {0,0,0,0}, o1 = {0,0,0,0}, o2 = {0,0,0,0}, o3 = {0,0,0,0};
    const float4* kp = (const float4*)(kb + ((size_t)b * KVN) * F + h * HD);
    const float4* vp = (const float4*)(vb + ((size_t)b * KVN) * F + h * HD);
    for (int kc = 0; kc < KVN; ++kc) {
        const float4* kk = kp + (size_t)kc * (F / 4);
        float4 k0 = kk[0], k1 = kk[1], k2v = kk[2], k3 = kk[3];
        float s = dot4(q0, k0) + dot4(q1, k1) + dot4(q2, k2v) + dot4(q3, k3);
        s = (mk[kc] > 0.f) ? s * 0.25f : -1e9f;
        float mn = fmaxf(m, s);
        float corr = expf(m - mn);
        float p = expf(s - mn);
        l = l * corr + p;
        const float4* vv = vp + (size_t)kc * (F / 4);
        float4 v0 = vv[0], v1 = vv[1], v2 = vv[2], v3 = vv[3];
        o0.x = o0.x*corr + p*v0.x; o0.y = o0.y*corr + p*v0.y; o0.z = o0.z*corr + p*v0.z; o0.w = o0.w*corr + p*v0.w;
        o1.x = o1.x*corr + p*v1.x; o1.y = o1.y*corr + p*v1.y; o1.z = o1.z*corr + p*v1.z; o1.w = o1.w*corr + p*v1.w;
        o2.x = o2.x*corr + p*v2.x; o2.y = o2.y*corr + p*v2.y; o2.z = o2.z*corr + p*v2.z; o2.w = o2.w*corr + p*v2.w;
        o3.x = o3.x*corr + p*v3.x; o3.y = o3.y*corr + p*v3.y; o3.z = o3.z*corr + p*v3.z; o3.w = o3.w*corr + p*v3.w;
        m = mn;
    }
    float inv = 1.f / l;
    o0.x *= inv; o0.y *= inv; o0.z *= inv; o0.w *= inv;
    o1.x *= inv; o1.y *= inv; o1.z *= inv; o1.w *= inv;
    o2.x *= inv; o2.y *= inv; o2.z *= inv; o2.w *= inv;
    o3.x *= inv; o3.y *= inv; o3.z *= inv; o3.w *= inv;
    float4* op = (float4*)(ao + ((size_t)b * N1 + qr) * F + h * HD);
    op[0] = o0; op[1] = o1; op[2] = o2; op[3] = o3;
}

// Kernel B2: out-proj + residual + layernorm. grid B*4, block 256, 8 rows/block.
// wave -> 2 rows, lane -> cols j, j+64. LN stats via full-wave shuffle.
__global__ __launch_bounds__(256) void k_proj_ln(
        const float* __restrict__ ao, const float* __restrict__ kvbuf,
        const float* __restrict__ wo_t,
        const float* __restrict__ ln_ego_g, const float* __restrict__ ln_ego_b,
        const float* __restrict__ ln_g, const float* __restrict__ ln_b,
        float* __restrict__ xln) {
    int gq = blockIdx.x & 3, b = blockIdx.x >> 2;
    int n0 = gq * 8;
    int tid = threadIdx.x; // 256
    int w = tid >> 6, j = tid & 63;
    int r0 = w * 2;
    __shared__ float as[8][F];
    for (int i = tid; i < 8 * F; i += 256) {
        int r = i >> 7, cc = i & 127;
        as[r][cc] = ao[((size_t)b * N1 + n0 + r) * F + cc];
    }
    __syncthreads();
    float acc[2][2] = {{0, 0}, {0, 0}};
    for (int k2 = 0; k2 < F; k2 += 4) {
        float4 w0 = *(const float4*)(wo_t + (size_t)j * F + k2);
        float4 w1 = *(const float4*)(wo_t + (size_t)(j + 64) * F + k2);
#pragma unroll
        for (int r = 0; r < 2; ++r) {
            float4 av4 = *(const float4*)&as[r0 + r][k2];
            acc[r][0] += dot4(av4, w0);
            acc[r][1] += dot4(av4, w1);
        }
    }
#pragma unroll
    for (int r = 0; r < 2; ++r) {
        int n = n0 + r0 + r;
        size_t base = ((size_t)b * KVN + n) * F;
        float x0 = kvbuf[base + j] + acc[r][0];
        float x1 = kvbuf[base + j + 64] + acc[r][1];
        float s1 = x0 + x1, s2 = x0 * x0 + x1 * x1;
#pragma unroll
        for (int off = 32; off > 0; off >>= 1) {
            s1 += __shfl_xor(s1, off, 64);
            s2 += __shfl_xor(s2, off, 64);
        }
        float mean = s1 * (1.f / F);
        float var = s2 * (1.f / F) - mean * mean;
        float rstd = rsqrtf(var + 1e-5f);
        const float* gg = (n == 0) ? ln_ego_g : ln_g;
        const float* bbv = (n == 0) ? ln_ego_b : ln_b;
        size_t ob = ((size_t)b * N1 + n) * F;
        xln[ob + j]      = (x0 - mean) * rstd * gg[j] + bbv[j];
        xln[ob + j + 64] = (x1 - mean) * rstd * gg[j + 64] + bbv[j + 64];
    }
}

// Kernel C: LSTM cell + (pred mode) output head + pos update + y.
// grid N1*8 = 256 blocks, block 256 (4 waves). Block: 16 batch rows (fixed n) x 512 gates.
// wave -> 4 rows; lane j -> cols j+64*i (i=0..7) covering all 4 gate blocks for
// features j and j+64 => no gate exchange needed. Weights: b128 along k from
// ORIGINAL (gate,k) layout, streaming.
__global__ __launch_bounds__(256) void k_lstm_pred(
        const float* __restrict__ xln,
        const float* __restrict__ ego_wih, const float* __restrict__ ego_whh,
        const float* __restrict__ ego_bih, const float* __restrict__ ego_bhh,
        const float* __restrict__ veh_wih, const float* __restrict__ veh_whh,
        const float* __restrict__ veh_bih, const float* __restrict__ veh_bhh,
        const float* __restrict__ h_in, const float* __restrict__ c_in,
        float* __restrict__ h_out, float* __restrict__ c_out,
        const float* __restrict__ out_ego_w, const float* __restrict__ out_ego_b,
        const float* __restrict__ out_w, const float* __restrict__ out_b,
        float* __restrict__ pred_pos, float* __restrict__ out,
        int mode, int step) {
    int n = blockIdx.x >> 3, bg = blockIdx.x & 7;
    int b0 = bg * 16;
    int tid = threadIdx.x; // 256
    int w = tid >> 6, j = tid & 63;
    int r0 = w * 4;
    const float *wih, *whh, *bih, *bhh;
    if (n == 0) { wih = ego_wih; whh = ego_whh; bih = ego_bih; bhh = ego_bhh; }
    else        { wih = veh_wih; whh = veh_whh; bih = veh_bih; bhh = veh_bhh; }
    __shared__ float xs[16][F];   // 8 KB
    __shared__ float hs[16][F];   // 8 KB
    __shared__ float h2s[16][F];  // 8 KB
    __shared__ float os[16][P6];  // 2.3 KB
    for (int i = tid; i < 16 * (F / 4); i += 256) {
        int r = i >> 5, c4 = i & 31;
        size_t bn = (size_t)(b0 + r) * N1 + n;
        *(float4*)&xs[r][c4 * 4] = *(const float4*)(xln  + bn * F + c4 * 4);
        *(float4*)&hs[r][c4 * 4] = *(const float4*)(h_in + bn * F + c4 * 4);
    }
    __syncthreads();
    float acc[4][8];
#pragma unroll
    for (int i = 0; i < 8; ++i) {
        float bsum = bih[64 * i + j] + bhh[64 * i + j];
#pragma unroll
        for (int r = 0; r < 4; ++r) acc[r][i] = bsum;
    }
    for (int k2 = 0; k2 < F; k2 += 4) {
        float4 xv[4], hv[4];
#pragma unroll
        for (int r = 0; r < 4; ++r) {
            xv[r] = *(const float4*)&xs[r0 + r][k2];
            hv[r] = *(const float4*)&hs[r0 + r][k2];
        }
#pragma unroll
        for (int i = 0; i < 8; ++i) {
            int col = 64 * i + j;
            float4 wa = *(const float4*)(wih + (size_t)col * F + k2);
            float4 wb = *(const float4*)(whh + (size_t)col * F + k2);
#pragma unroll
            for (int r = 0; r < 4; ++r)
                acc[r][i] += dot4(xv[r], wa) + dot4(hv[r], wb);
        }
    }
    // lane j holds gates for features j (i=0,2,4,6) and j+64 (i=1,3,5,7)
#pragma unroll
    for (int r = 0; r < 4; ++r) {
        size_t bn = (size_t)(b0 + r0 + r) * N1 + n;
#pragma unroll
        for (int half = 0; half < 2; ++half) {
            int f = j + 64 * half;
            float ig = acc[r][0 + half], fg = acc[r][2 + half];
            float gg = acc[r][4 + half], og = acc[r][6 + half];
            float cold = c_in[bn * F + f];
            float c2 = sigmoidf(fg) * cold + sigmoidf(ig) * tanhf(gg);
            float h2 = sigmoidf(og) * tanhf(c2);
            c_out[bn * F + f] = c2;
            h_out[bn * F + f] = h2;
            h2s[r0 + r][f] = h2;
        }
    }
    if (mode == 1) {
        const float* W  = (n == 0) ? out_ego_w : out_w;
        const float* bb = (n == 0) ? out_ego_b : out_b;
        __syncthreads();
        for (int i = tid; i < 16 * P6; i += 256) {
            int r = i / P6, jj = i % P6;
            float a = bb[jj];
            for (int k2 = 0; k2 < F; ++k2) a += h2s[r][k2] * W[k2 * P6 + jj];
            os[r][jj] = a;
        }
        __syncthreads();
        if (tid < 16 * NP) {
            int r = tid / NP, p = tid % NP;
            size_t bn = (size_t)(b0 + r) * N1 + n;
            float dl = os[r][p * 6 + 0], yaw = os[r][p * 6 + 1];
            float* pp = pred_pos + (bn * NP + p) * 2;
            float px = pp[0] + dl * cosf(yaw);
            float py = pp[1] + dl * sinf(yaw);
            pp[0] = px; pp[1] = py;
            float* y = out + (size_t)step * B * N1 * P6 + (bn * NP + p) * 6;
            y[0] = px; y[1] = py;
            y[2] = os[r][p * 6 + 2]; y[3] = os[r][p * 6 + 3];
            y[4] = os[r][p * 6 + 4]; y[5] = os[r][p * 6 + 5];
        }
    }
}

// ---------------- launcher ----------------
extern "C" void kernel_launch(void* const* d_in, const int* in_sizes, int n_in,
                              void* d_out, int out_size, void* d_ws, size_t ws_size,
                              hipStream_t stream) {
    const float* input      = (const float*)d_in[0];
    const float* init_pos   = (const float*)d_in[1];
    const float* lane_input = (const float*)d_in[2];
    const float* mask_input = (const float*)d_in[3];
    const float* lane_mask  = (const float*)d_in[4];
    const float* conv_w     = (const float*)d_in[5];
    const float* conv_b     = (const float*)d_in[6];
    const float* pos_w      = (const float*)d_in[7];
    const float* pos_b      = (const float*)d_in[8];
    const float* lane_w1    = (const float*)d_in[9];
    const float* lane_b1    = (const float*)d_in[10];
    const float* lane_w2    = (const float*)d_in[11];
    const float* lane_b2    = (const float*)d_in[12];
    const float* lane_to_f  = (const float*)d_in[13];
    const float* wq         = (const float*)d_in[14];
    const float* wk         = (const float*)d_in[15];
    const float* wv         = (const float*)d_in[16];
    const float* wo         = (const float*)d_in[17];
    const float* ln_ego_g   = (const float*)d_in[18];
    const float* ln_ego_b   = (const float*)d_in[19];
    const float* ln_g       = (const float*)d_in[20];
    const float* ln_b       = (const float*)d_in[21];
    const float* ego_wih    = (const float*)d_in[22];
    const float* ego_whh    = (const float*)d_in[23];
    const float* ego_bih    = (const float*)d_in[24];
    const float* ego_bhh    = (const float*)d_in[25];
    const float* veh_wih    = (const float*)d_in[26];
    const float* veh_whh    = (const float*)d_in[27];
    const float* veh_bih    = (const float*)d_in[28];
    const float* veh_bhh    = (const float*)d_in[29];
    const float* out_ego_w  = (const float*)d_in[30];
    const float* out_ego_b  = (const float*)d_in[31];
    const float* out_w      = (const float*)d_in[32];
    const float* out_b      = (const float*)d_in[33];

    float* out = (float*)d_out;
    float* ws = (float*)d_ws;

    // workspace layout (floats)
    float* kv       = ws;                        // B*KVN*F
    float* qb       = kv + (size_t)B * KVN * F;  // B*N1*F
    float* kb       = qb + (size_t)B * N1 * F;   // B*KVN*F
    float* vb       = kb + (size_t)B * KVN * F;  // B*KVN*F
    float* ao       = vb + (size_t)B * KVN * F;  // B*N1*F
    float* xln      = ao + (size_t)B * N1 * F;   // B*N1*F
    float* h0       = xln + (size_t)B * N1 * F;
    float* h1p      = h0 + (size_t)B * N1 * F;
    float* c0       = h1p + (size_t)B * N1 * F;
    float* c1p      = c0 + (size_t)B * N1 * F;
    float* hist_pos = c1p + (size_t)B * N1 * F;             // HH*B*N1*2
    float* pred_pos = hist_pos + (size_t)HH * B * N1 * 2;   // B*N1*NP*2
    float* wqkvo_t  = pred_pos + (size_t)B * N1 * NP * 2;   // 4 * F*F
    float* wq_t = wqkvo_t;
    float* wk_t = wqkvo_t + (size_t)F * F;
    float* wv_t = wqkvo_t + (size_t)2 * F * F;
    float* wo_t = wqkvo_t + (size_t)3 * F * F;

    float* hb[2] = {h0, h1p};
    float* cb[2] = {c0, c1p};

    // ---- init ----
    hipMemsetAsync(h0, 0, (size_t)B * N1 * F * sizeof(float), stream);
    hipMemsetAsync(c0, 0, (size_t)B * N1 * F * sizeof(float), stream);
    k_transpose4<<<4 * F, F, 0, stream>>>(wq, wk, wv, wo, wqkvo_t);
    k_lane_tok<<<B * L, 64, 0, stream>>>(lane_input, lane_w1, lane_b1, lane_w2, lane_b2,
                                         lane_to_f, kv);
    k_hist_pos<<<(B * N1 + 255) / 256, 256, 0, stream>>>(input, init_pos, hist_pos, pred_pos);
    k_lane_kv<<<B * 8, 256, 0, stream>>>(kv, wk_t, wv_t, kb, vb);

    int cur = 0;
    for (int step = 0; step < HH + LEN; ++step) {
        int mode = (step < HH) ? 0 : 1;
        int t = (mode == 0) ? step : 0;
        int s = (mode == 0) ? 0 : step - HH;
        k_tok_qkv<<<B * 4, 256, 0, stream>>>(input, hist_pos, hb[cur], pred_pos,
                                             conv_w, conv_b, pos_w, pos_b,
                                             wq_t, wk_t, wv_t, kv, qb, kb, vb, mode, t);
        k_attn<<<B * 4, 64, 0, stream>>>(qb, kb, vb, mask_input, lane_mask, ao);
        k_proj_ln<<<B * 4, 256, 0, stream>>>(ao, kv, wo_t, ln_ego_g, ln_ego_b, ln_g, ln_b, xln);
        k_lstm_pred<<<N1 * 8, 256, 0, stream>>>(xln, ego_wih, ego_whh, ego_bih, ego_bhh,
                                                veh_wih, veh_whh, veh_bih, veh_bhh,
                                                hb[cur], cb[cur], hb[1 - cur], cb[1 - cur],
                                                out_ego_w, out_ego_b, out_w, out_b,
                                                pred_pos, out, mode, s);
        cur ^= 1;
    }
}

// Round 6
// 8978.550 us; speedup vs baseline: 1.3389x; 1.3389x over previous
//
#include <hip/hip_runtime.h>
#include <hip/hip_bf16.h>
#include <math.h>

// ---------------- constants (fixed by setup_inputs) ----------------
constexpr int B   = 128;   // batch
constexpr int N1  = 32;    // agents (1 ego + 31 veh)
constexpr int HH  = 20;    // history steps (T-2)
constexpr int L   = 64;    // lanes
constexpr int PTS = 10;    // points per lane
constexpr int F   = 128;   // feature size
constexpr int LF  = 64;    // lane feature
constexpr int NH  = 8;     // heads
constexpr int HD  = 16;    // head dim
constexpr int KVN = 96;    // kv tokens = 32 agents + 64 lanes
constexpr int G4  = 512;   // 4*F lstm gates
constexpr int NP  = 6;     // num preds
constexpr int P6  = 36;    // NP*6
constexpr int LEN = 30;    // len_pred

__device__ __forceinline__ float sigmoidf(float x) { return 1.f / (1.f + expf(-x)); }
__device__ __forceinline__ float dot4(float4 a, float4 b) {
    return a.x * b.x + a.y * b.y + a.z * b.z + a.w * b.w;
}

// ---------------- one-time kernels ----------------

// lane MLP -> lane tokens (kv rows 32..95). One wave per (b,l).
__global__ __launch_bounds__(64) void k_lane_tok(
        const float* __restrict__ lane_input,
        const float* __restrict__ w1, const float* __restrict__ b1,
        const float* __restrict__ w2, const float* __restrict__ b2,
        const float* __restrict__ to_f,
        float* __restrict__ kvbuf) {
    int bl = blockIdx.x; int b = bl / L, l = bl % L;
    int j = threadIdx.x; // 64
    __shared__ float w1s[2 * LF];
    __shared__ float b1s[LF];
    __shared__ float ml[LF];
    w1s[j] = w1[j]; w1s[LF + j] = w1[LF + j]; b1s[j] = b1[j];
    float x0[PTS], x1[PTS];
#pragma unroll
    for (int p = 0; p < PTS; ++p) {
        x0[p] = lane_input[((size_t)(b * L + l) * PTS + p) * 2 + 0];
        x1[p] = lane_input[((size_t)(b * L + l) * PTS + p) * 2 + 1];
    }
    __syncthreads();
    float mp[PTS];
#pragma unroll
    for (int p = 0; p < PTS; ++p) mp[p] = 0.f;
    for (int hh = 0; hh < LF; ++hh) {
        float w10 = w1s[hh], w11 = w1s[LF + hh], b1h = b1s[hh];
        float wv = w2[hh * LF + j];
#pragma unroll
        for (int p = 0; p < PTS; ++p) {
            float h1v = fmaxf(x0[p] * w10 + x1[p] * w11 + b1h, 0.f);
            mp[p] += h1v * wv;
        }
    }
    float b2j = b2[j];
    float m = 0.f;
#pragma unroll
    for (int p = 0; p < PTS; ++p) m += fmaxf(mp[p] + b2j, 0.f);
    ml[j] = m * (1.f / PTS);
    __syncthreads();
    float* outp = kvbuf + ((size_t)(b * KVN) + 32 + l) * F;
    float acc0 = 0.f, acc1 = 0.f;
    for (int j2 = 0; j2 < LF; ++j2) {
        float mv = ml[j2];
        acc0 += mv * to_f[j2 * F + j];
        acc1 += mv * to_f[j2 * F + 64 + j];
    }
    outp[j] = acc0; outp[64 + j] = acc1;
}

// lane K/V: project constant lane tokens once. 8 rows per block.
__global__ __launch_bounds__(256) void k_lane_kv(
        const float* __restrict__ kvbuf,
        const float* __restrict__ wk_t, const float* __restrict__ wv_t,
        float* __restrict__ kb, float* __restrict__ vb) {
    int g = blockIdx.x & 7, b = blockIdx.x >> 3;
    int n0 = 32 + g * 8;
    int tid = threadIdx.x; // 256 = 4 waves
    int w = tid >> 6, j = tid & 63;
    int r0 = (w >> 1) * 4;
    int c = (w & 1) * 64 + j;
    __shared__ float tok[8][F];
    for (int i = tid; i < 8 * F; i += 256) {
        int r = i >> 7, cc = i & 127;
        tok[r][cc] = kvbuf[((size_t)b * KVN + n0 + r) * F + cc];
    }
    __syncthreads();
    float ak[4] = {0, 0, 0, 0}, av[4] = {0, 0, 0, 0};
    for (int k2 = 0; k2 < F; k2 += 4) {
        float4 wkv = *(const float4*)(wk_t + (size_t)c * F + k2);
        float4 wvv = *(const float4*)(wv_t + (size_t)c * F + k2);
#pragma unroll
        for (int r = 0; r < 4; ++r) {
            float4 xv = *(const float4*)&tok[r0 + r][k2];
            ak[r] += dot4(xv, wkv); av[r] += dot4(xv, wvv);
        }
    }
#pragma unroll
    for (int r = 0; r < 4; ++r) {
        int n = n0 + r0 + r;
        kb[((size_t)b * KVN + n) * F + c] = ak[r];
        vb[((size_t)b * KVN + n) * F + c] = av[r];
    }
}

__global__ void k_hist_pos(const float* __restrict__ input,
                           const float* __restrict__ init_pos,
                           float* __restrict__ hist_pos,
                           float* __restrict__ pred_pos) {
    int idx = blockIdx.x * blockDim.x + threadIdx.x;
    if (idx >= B * N1) return;
    float px = init_pos[idx * 2], py = init_pos[idx * 2 + 1];
    int b = idx / N1, n = idx % N1;
    for (int t = 0; t < HH; ++t) {
        const float* ip = input + ((size_t)(t * B + b) * N1 + n) * 2;
        float dl = ip[0], yaw = ip[1];
        px += dl * cosf(yaw);
        py += dl * sinf(yaw);
        float* hp = hist_pos + ((size_t)(t * B + b) * N1 + n) * 2;
        hp[0] = px; hp[1] = py;
    }
#pragma unroll
    for (int p = 0; p < NP; ++p) {
        pred_pos[((size_t)idx * NP + p) * 2 + 0] = px;
        pred_pos[((size_t)idx * NP + p) * 2 + 1] = py;
    }
}

// transpose wq,wk,wv,wo (each F x F, k-major) -> (col, k) layout
__global__ void k_transpose4(const float* __restrict__ w0, const float* __restrict__ w1,
                             const float* __restrict__ w2, const float* __restrict__ w3,
                             float* __restrict__ wt) {
    int m = blockIdx.x >> 7, c = blockIdx.x & 127;
    int k = threadIdx.x; // 128
    const float* src = (m == 0) ? w0 : (m == 1) ? w1 : (m == 2) ? w2 : w3;
    wt[(size_t)m * F * F + (size_t)c * F + k] = src[(size_t)k * F + c];
}

// transpose 4 LSTM weight mats (G4,F) -> (F,G4): wt[m][k][c] = w[m][c][k]
__global__ void k_transpose_lstm(const float* __restrict__ w0, const float* __restrict__ w1,
                                 const float* __restrict__ w2, const float* __restrict__ w3,
                                 float* __restrict__ wt) {
    int i = blockIdx.x * blockDim.x + threadIdx.x;
    if (i >= 4 * G4 * F) return;
    int m = i / (G4 * F), rem = i % (G4 * F);
    int c = rem / F, k = rem % F;
    const float* src = (m == 0) ? w0 : (m == 1) ? w1 : (m == 2) ? w2 : w3;
    wt[(size_t)m * G4 * F + (size_t)k * G4 + c] = src[rem];
}

// ---------------- per-step kernels ----------------

// Kernel A: build agent tokens + q/k/v projections. grid B*4, block 256, 8 rows/block.
__global__ __launch_bounds__(256) void k_tok_qkv(
        const float* __restrict__ input, const float* __restrict__ hist_pos,
        const float* __restrict__ h, const float* __restrict__ pred_pos,
        const float* __restrict__ conv_w, const float* __restrict__ conv_b,
        const float* __restrict__ pos_w, const float* __restrict__ pos_b,
        const float* __restrict__ wq_t, const float* __restrict__ wk_t,
        const float* __restrict__ wv_t,
        float* __restrict__ kvbuf, float* __restrict__ qb,
        float* __restrict__ kb, float* __restrict__ vb,
        int mode, int t) {
    int g = blockIdx.x & 3, b = blockIdx.x >> 2;
    int n0 = g * 8;
    int tid = threadIdx.x;
    int w = tid >> 6, j = tid & 63;
    int r0 = (w >> 1) * 4;
    int c = (w & 1) * 64 + j;
    __shared__ float tok[8][F];
    __shared__ float mpos[8][2];
    if (mode == 1 && tid < 8) {
        const float* pp = pred_pos + ((size_t)(b * N1 + n0 + tid)) * NP * 2;
        float mx = 0.f, my = 0.f;
#pragma unroll
        for (int p = 0; p < NP; ++p) { mx += pp[p * 2]; my += pp[p * 2 + 1]; }
        mpos[tid][0] = mx * (1.f / NP); mpos[tid][1] = my * (1.f / NP);
    }
    __syncthreads();
    for (int i = tid; i < 8 * F; i += 256) {
        int r = i >> 7, cc = i & 127;
        int n = n0 + r;
        float acc;
        if (mode == 0) {
            acc = conv_b[cc];
#pragma unroll
            for (int kt = 0; kt < 3; ++kt) {
                const float* ip = input + ((size_t)((t + kt) * B + b) * N1 + n) * 2;
                acc += ip[0] * conv_w[(cc * 2 + 0) * 3 + kt] + ip[1] * conv_w[(cc * 2 + 1) * 3 + kt];
            }
            const float* hp = hist_pos + ((size_t)(t * B + b) * N1 + n) * 2;
            acc += hp[0] * pos_w[cc] + hp[1] * pos_w[F + cc] + pos_b[cc];
        } else {
            acc = h[((size_t)b * N1 + n) * F + cc]
                + mpos[r][0] * pos_w[cc] + mpos[r][1] * pos_w[F + cc] + pos_b[cc];
        }
        tok[r][cc] = acc;
        kvbuf[((size_t)b * KVN + n) * F + cc] = acc;
    }
    __syncthreads();
    float aq[4] = {0, 0, 0, 0}, ak[4] = {0, 0, 0, 0}, av[4] = {0, 0, 0, 0};
    for (int k2 = 0; k2 < F; k2 += 4) {
        float4 wqv = *(const float4*)(wq_t + (size_t)c * F + k2);
        float4 wkv = *(const float4*)(wk_t + (size_t)c * F + k2);
        float4 wvv = *(const float4*)(wv_t + (size_t)c * F + k2);
#pragma unroll
        for (int r = 0; r < 4; ++r) {
            float4 xv = *(const float4*)&tok[r0 + r][k2];
            aq[r] += dot4(xv, wqv); ak[r] += dot4(xv, wkv); av[r] += dot4(xv, wvv);
        }
    }
#pragma unroll
    for (int r = 0; r < 4; ++r) {
        int n = n0 + r0 + r;
        qb[((size_t)b * N1 + n) * F + c]  = aq[r];
        kb[((size_t)b * KVN + n) * F + c] = ak[r];
        vb[((size_t)b * KVN + n) * F + c] = av[r];
    }
}

// Kernel B1: attention. grid B*NH = 1024 blocks, 1 wave each.
// lane = (qr 0..31, dh 0..1): q-row x d-half(8). Score via partial dot +
// shfl_xor(32). Two interleaved online-softmax chains (kc, kc+48) for ILP.
__global__ __launch_bounds__(64) void k_attn(
        const float* __restrict__ qb, const float* __restrict__ kb,
        const float* __restrict__ vb,
        const float* __restrict__ mask_in, const float* __restrict__ lane_mask,
        float* __restrict__ ao) {
    int h = blockIdx.x & 7, b = blockIdx.x >> 3;
    int t = threadIdx.x;
    int qr = t & 31, dh = t >> 5;
    __shared__ float mk[KVN];
    if (t < KVN) {
        int i = t;
        mk[i] = (i < N1) ? mask_in[b * N1 + i] : lane_mask[b * L + (i - N1)];
    }
    if (t < KVN - 64) {
        int i = t + 64;
        mk[i] = lane_mask[b * L + (i - N1)];
    }
    const float* qp = qb + ((size_t)b * N1 + qr) * F + h * HD + dh * 8;
    float4 q0 = *(const float4*)qp, q1 = *(const float4*)(qp + 4);
    __syncthreads();
    const float* kbase = kb + (size_t)b * KVN * F + h * HD + dh * 8;
    const float* vbase = vb + (size_t)b * KVN * F + h * HD + dh * 8;
    float mA = -1e30f, lA = 0.f, mB = -1e30f, lB = 0.f;
    float4 oA0 = {0,0,0,0}, oA1 = {0,0,0,0}, oB0 = {0,0,0,0}, oB1 = {0,0,0,0};
    constexpr int HALF = KVN / 2; // 48
    for (int kc = 0; kc < HALF; ++kc) {
        int ka = kc, kb2 = kc + HALF;
        float4 a0 = *(const float4*)(kbase + (size_t)ka * F);
        float4 a1 = *(const float4*)(kbase + (size_t)ka * F + 4);
        float4 b0 = *(const float4*)(kbase + (size_t)kb2 * F);
        float4 b1 = *(const float4*)(kbase + (size_t)kb2 * F + 4);
        float shA = dot4(q0, a0) + dot4(q1, a1);
        float shB = dot4(q0, b0) + dot4(q1, b1);
        float sA = shA + __shfl_xor(shA, 32, 64);
        float sB = shB + __shfl_xor(shB, 32, 64);
        sA = (mk[ka]  > 0.f) ? sA * 0.25f : -1e9f;
        sB = (mk[kb2] > 0.f) ? sB * 0.25f : -1e9f;
        float mnA = fmaxf(mA, sA), mnB = fmaxf(mB, sB);
        float cA = expf(mA - mnA), cB = expf(mB - mnB);
        float pA = expf(sA - mnA), pB = expf(sB - mnB);
        lA = lA * cA + pA; lB = lB * cB + pB;
        float4 va0 = *(const float4*)(vbase + (size_t)ka * F);
        float4 va1 = *(const float4*)(vbase + (size_t)ka * F + 4);
        float4 vb0 = *(const float4*)(vbase + (size_t)kb2 * F);
        float4 vb1 = *(const float4*)(vbase + (size_t)kb2 * F + 4);
        oA0.x = fmaf(oA0.x, cA, pA * va0.x); oA0.y = fmaf(oA0.y, cA, pA * va0.y);
        oA0.z = fmaf(oA0.z, cA, pA * va0.z); oA0.w = fmaf(oA0.w, cA, pA * va0.w);
        oA1.x = fmaf(oA1.x, cA, pA * va1.x); oA1.y = fmaf(oA1.y, cA, pA * va1.y);
        oA1.z = fmaf(oA1.z, cA, pA * va1.z); oA1.w = fmaf(oA1.w, cA, pA * va1.w);
        oB0.x = fmaf(oB0.x, cB, pB * vb0.x); oB0.y = fmaf(oB0.y, cB, pB * vb0.y);
        oB0.z = fmaf(oB0.z, cB, pB * vb0.z); oB0.w = fmaf(oB0.w, cB, pB * vb0.w);
        oB1.x = fmaf(oB1.x, cB, pB * vb1.x); oB1.y = fmaf(oB1.y, cB, pB * vb1.y);
        oB1.z = fmaf(oB1.z, cB, pB * vb1.z); oB1.w = fmaf(oB1.w, cB, pB * vb1.w);
        mA = mnA; mB = mnB;
    }
    // merge chains
    float mn = fmaxf(mA, mB);
    float fa = expf(mA - mn), fb = expf(mB - mn);
    float l = lA * fa + lB * fb;
    float inv = 1.f / l;
    float ia = fa * inv, ib = fb * inv;
    float4 o0, o1;
    o0.x = oA0.x * ia + oB0.x * ib; o0.y = oA0.y * ia + oB0.y * ib;
    o0.z = oA0.z * ia + oB0.z * ib; o0.w = oA0.w * ia + oB0.w * ib;
    o1.x = oA1.x * ia + oB1.x * ib; o1.y = oA1.y * ia + oB1.y * ib;
    o1.z = oA1.z * ia + oB1.z * ib; o1.w = oA1.w * ia + oB1.w * ib;
    float* op = ao + ((size_t)b * N1 + qr) * F + h * HD + dh * 8;
    *(float4*)op = o0; *(float4*)(op + 4) = o1;
}

// Kernel B2: out-proj + residual + layernorm. grid B*4, block 256, 8 rows/block.
__global__ __launch_bounds__(256) void k_proj_ln(
        const float* __restrict__ ao, const float* __restrict__ kvbuf,
        const float* __restrict__ wo_t,
        const float* __restrict__ ln_ego_g, const float* __restrict__ ln_ego_b,
        const float* __restrict__ ln_g, const float* __restrict__ ln_b,
        float* __restrict__ xln) {
    int gq = blockIdx.x & 3, b = blockIdx.x >> 2;
    int n0 = gq * 8;
    int tid = threadIdx.x; // 256
    int w = tid >> 6, j = tid & 63;
    int r0 = w * 2;
    __shared__ float as[8][F];
    for (int i = tid; i < 8 * F; i += 256) {
        int r = i >> 7, cc = i & 127;
        as[r][cc] = ao[((size_t)b * N1 + n0 + r) * F + cc];
    }
    __syncthreads();
    float acc[2][2] = {{0, 0}, {0, 0}};
    for (int k2 = 0; k2 < F; k2 += 4) {
        float4 w0 = *(const float4*)(wo_t + (size_t)j * F + k2);
        float4 w1 = *(const float4*)(wo_t + (size_t)(j + 64) * F + k2);
#pragma unroll
        for (int r = 0; r < 2; ++r) {
            float4 av4 = *(const float4*)&as[r0 + r][k2];
            acc[r][0] += dot4(av4, w0);
            acc[r][1] += dot4(av4, w1);
        }
    }
#pragma unroll
    for (int r = 0; r < 2; ++r) {
        int n = n0 + r0 + r;
        size_t base = ((size_t)b * KVN + n) * F;
        float x0 = kvbuf[base + j] + acc[r][0];
        float x1 = kvbuf[base + j + 64] + acc[r][1];
        float s1 = x0 + x1, s2 = x0 * x0 + x1 * x1;
#pragma unroll
        for (int off = 32; off > 0; off >>= 1) {
            s1 += __shfl_xor(s1, off, 64);
            s2 += __shfl_xor(s2, off, 64);
        }
        float mean = s1 * (1.f / F);
        float var = s2 * (1.f / F) - mean * mean;
        float rstd = rsqrtf(var + 1e-5f);
        const float* gg = (n == 0) ? ln_ego_g : ln_g;
        const float* bbv = (n == 0) ? ln_ego_b : ln_b;
        size_t ob = ((size_t)b * N1 + n) * F;
        xln[ob + j]      = (x0 - mean) * rstd * gg[j] + bbv[j];
        xln[ob + j + 64] = (x1 - mean) * rstd * gg[j + 64] + bbv[j + 64];
    }
}

// Kernel C: LSTM cell + (pred mode) output head + pos update + y.
// grid N1*8 = 256 blocks, block 256 (4 waves), 16 batch rows of one agent n.
// Weights in (k, col) layout: lane ln owns cols {4ln+q, 256+4ln+q} -> fully
// coalesced float4 weight loads. Gate recombination via shfl_xor(32).
__global__ __launch_bounds__(256) void k_lstm_pred(
        const float* __restrict__ xln,
        const float* __restrict__ ego_wih_t, const float* __restrict__ ego_whh_t,
        const float* __restrict__ ego_bih, const float* __restrict__ ego_bhh,
        const float* __restrict__ veh_wih_t, const float* __restrict__ veh_whh_t,
        const float* __restrict__ veh_bih, const float* __restrict__ veh_bhh,
        const float* __restrict__ h_in, const float* __restrict__ c_in,
        float* __restrict__ h_out, float* __restrict__ c_out,
        const float* __restrict__ out_ego_w, const float* __restrict__ out_ego_b,
        const float* __restrict__ out_w, const float* __restrict__ out_b,
        float* __restrict__ pred_pos, float* __restrict__ out,
        int mode, int step) {
    int n = blockIdx.x >> 3, bg = blockIdx.x & 7;
    int b0 = bg * 16;
    int tid = threadIdx.x; // 256
    int wv = tid >> 6, ln = tid & 63;
    int r0 = wv * 4;
    int jj = ln & 31, dh = ln >> 5;
    const float *wih, *whh, *bih, *bhh;
    if (n == 0) { wih = ego_wih_t; whh = ego_whh_t; bih = ego_bih; bhh = ego_bhh; }
    else        { wih = veh_wih_t; whh = veh_whh_t; bih = veh_bih; bhh = veh_bhh; }
    __shared__ float xs[16][F];   // 8 KB
    __shared__ float hs[16][F];   // 8 KB
    __shared__ float h2s[16][F];  // 8 KB
    __shared__ float os[16][P6];
    for (int i = tid; i < 16 * (F / 4); i += 256) {
        int r = i >> 5, c4 = i & 31;
        size_t bn = (size_t)(b0 + r) * N1 + n;
        *(float4*)&xs[r][c4 * 4] = *(const float4*)(xln  + bn * F + c4 * 4);
        *(float4*)&hs[r][c4 * 4] = *(const float4*)(h_in + bn * F + c4 * 4);
    }
    __syncthreads();
    // acc[r][i2*4+q] for cols 256*i2 + 4*ln + q
    float acc[4][8];
    {
        float4 bi0 = *(const float4*)(bih + 4 * ln);
        float4 bi1 = *(const float4*)(bih + 256 + 4 * ln);
        float4 bh0 = *(const float4*)(bhh + 4 * ln);
        float4 bh1 = *(const float4*)(bhh + 256 + 4 * ln);
        float bs[8] = {bi0.x + bh0.x, bi0.y + bh0.y, bi0.z + bh0.z, bi0.w + bh0.w,
                       bi1.x + bh1.x, bi1.y + bh1.y, bi1.z + bh1.z, bi1.w + bh1.w};
#pragma unroll
        for (int r = 0; r < 4; ++r)
#pragma unroll
            for (int q = 0; q < 8; ++q) acc[r][q] = bs[q];
    }
    for (int k4 = 0; k4 < F; k4 += 4) {
        float4 xv[4], hv[4];
#pragma unroll
        for (int r = 0; r < 4; ++r) {
            xv[r] = *(const float4*)&xs[r0 + r][k4];
            hv[r] = *(const float4*)&hs[r0 + r][k4];
        }
#pragma unroll
        for (int kk = 0; kk < 4; ++kk) {
            int k2 = k4 + kk;
            float4 wa0 = *(const float4*)(wih + (size_t)k2 * G4 + 4 * ln);
            float4 wa1 = *(const float4*)(wih + (size_t)k2 * G4 + 256 + 4 * ln);
            float4 wb0 = *(const float4*)(whh + (size_t)k2 * G4 + 4 * ln);
            float4 wb1 = *(const float4*)(whh + (size_t)k2 * G4 + 256 + 4 * ln);
#pragma unroll
            for (int r = 0; r < 4; ++r) {
                float x = ((const float*)&xv[r])[kk];
                float hc = ((const float*)&hv[r])[kk];
                acc[r][0] += x * wa0.x + hc * wb0.x;
                acc[r][1] += x * wa0.y + hc * wb0.y;
                acc[r][2] += x * wa0.z + hc * wb0.z;
                acc[r][3] += x * wa0.w + hc * wb0.w;
                acc[r][4] += x * wa1.x + hc * wb1.x;
                acc[r][5] += x * wa1.y + hc * wb1.y;
                acc[r][6] += x * wa1.z + hc * wb1.z;
                acc[r][7] += x * wa1.w + hc * wb1.w;
            }
        }
    }
    // lane dh=0: acc[q]=i-gate[4jj+q], acc[4+q]=g-gate; dh=1: f-gate, o-gate.
    // Exchange with partner lane (ln^32), then each lane finalizes 2 features.
#pragma unroll
    for (int r = 0; r < 4; ++r) {
        float ex[8];
#pragma unroll
        for (int q = 0; q < 8; ++q) ex[q] = __shfl_xor(acc[r][q], 32, 64);
        size_t bn = (size_t)(b0 + r0 + r) * N1 + n;
        int f0 = 4 * jj + 2 * dh;
        float2 cold = *(const float2*)(c_in + bn * F + f0);
        float2 c2v, h2v;
#pragma unroll
        for (int u = 0; u < 2; ++u) {
            int q = 2 * dh + u;
            float ig = dh ? ex[q]     : acc[r][q];
            float fg = dh ? acc[r][q] : ex[q];
            float gg = dh ? ex[4 + q]     : acc[r][4 + q];
            float og = dh ? acc[r][4 + q] : ex[4 + q];
            float co = (u == 0) ? cold.x : cold.y;
            float c2 = sigmoidf(fg) * co + sigmoidf(ig) * tanhf(gg);
            float h2 = sigmoidf(og) * tanhf(c2);
            if (u == 0) { c2v.x = c2; h2v.x = h2; } else { c2v.y = c2; h2v.y = h2; }
        }
        *(float2*)(c_out + bn * F + f0) = c2v;
        *(float2*)(h_out + bn * F + f0) = h2v;
        *(float2*)&h2s[r0 + r][f0] = h2v;
    }
    if (mode == 1) {
        const float* W  = (n == 0) ? out_ego_w : out_w;
        const float* bb = (n == 0) ? out_ego_b : out_b;
        __syncthreads();
        for (int i = tid; i < 16 * P6; i += 256) {
            int r = i / P6, jo = i % P6;
            float a = bb[jo];
            for (int k4 = 0; k4 < F; k4 += 4) {
                float4 hx = *(const float4*)&h2s[r][k4];
                a += hx.x * W[(k4    ) * P6 + jo] + hx.y * W[(k4 + 1) * P6 + jo]
                   + hx.z * W[(k4 + 2) * P6 + jo] + hx.w * W[(k4 + 3) * P6 + jo];
            }
            os[r][jo] = a;
        }
        __syncthreads();
        if (tid < 16 * NP) {
            int r = tid / NP, p = tid % NP;
            size_t bn = (size_t)(b0 + r) * N1 + n;
            float dl = os[r][p * 6 + 0], yaw = os[r][p * 6 + 1];
            float* pp = pred_pos + (bn * NP + p) * 2;
            float px = pp[0] + dl * cosf(yaw);
            float py = pp[1] + dl * sinf(yaw);
            pp[0] = px; pp[1] = py;
            float* y = out + (size_t)step * B * N1 * P6 + (bn * NP + p) * 6;
            y[0] = px; y[1] = py;
            y[2] = os[r][p * 6 + 2]; y[3] = os[r][p * 6 + 3];
            y[4] = os[r][p * 6 + 4]; y[5] = os[r][p * 6 + 5];
        }
    }
}

// ---------------- launcher ----------------
extern "C" void kernel_launch(void* const* d_in, const int* in_sizes, int n_in,
                              void* d_out, int out_size, void* d_ws, size_t ws_size,
                              hipStream_t stream) {
    const float* input      = (const float*)d_in[0];
    const float* init_pos   = (const float*)d_in[1];
    const float* lane_input = (const float*)d_in[2];
    const float* mask_input = (const float*)d_in[3];
    const float* lane_mask  = (const float*)d_in[4];
    const float* conv_w     = (const float*)d_in[5];
    const float* conv_b     = (const float*)d_in[6];
    const float* pos_w      = (const float*)d_in[7];
    const float* pos_b      = (const float*)d_in[8];
    const float* lane_w1    = (const float*)d_in[9];
    const float* lane_b1    = (const float*)d_in[10];
    const float* lane_w2    = (const float*)d_in[11];
    const float* lane_b2    = (const float*)d_in[12];
    const float* lane_to_f  = (const float*)d_in[13];
    const float* wq         = (const float*)d_in[14];
    const float* wk         = (const float*)d_in[15];
    const float* wv         = (const float*)d_in[16];
    const float* wo         = (const float*)d_in[17];
    const float* ln_ego_g   = (const float*)d_in[18];
    const float* ln_ego_b   = (const float*)d_in[19];
    const float* ln_g       = (const float*)d_in[20];
    const float* ln_b       = (const float*)d_in[21];
    const float* ego_wih    = (const float*)d_in[22];
    const float* ego_whh    = (const float*)d_in[23];
    const float* ego_bih    = (const float*)d_in[24];
    const float* ego_bhh    = (const float*)d_in[25];
    const float* veh_wih    = (const float*)d_in[26];
    const float* veh_whh    = (const float*)d_in[27];
    const float* veh_bih    = (const float*)d_in[28];
    const float* veh_bhh    = (const float*)d_in[29];
    const float* out_ego_w  = (const float*)d_in[30];
    const float* out_ego_b  = (const float*)d_in[31];
    const float* out_w      = (const float*)d_in[32];
    const float* out_b      = (const float*)d_in[33];

    float* out = (float*)d_out;
    float* ws = (float*)d_ws;

    // workspace layout (floats)
    float* kv       = ws;                        // B*KVN*F
    float* qb       = kv + (size_t)B * KVN * F;  // B*N1*F
    float* kb       = qb + (size_t)B * N1 * F;   // B*KVN*F
    float* vb       = kb + (size_t)B * KVN * F;  // B*KVN*F
    float* ao       = vb + (size_t)B * KVN * F;  // B*N1*F
    float* xln      = ao + (size_t)B * N1 * F;   // B*N1*F
    float* h0       = xln + (size_t)B * N1 * F;
    float* h1p      = h0 + (size_t)B * N1 * F;
    float* c0       = h1p + (size_t)B * N1 * F;
    float* c1p      = c0 + (size_t)B * N1 * F;
    float* hist_pos = c1p + (size_t)B * N1 * F;             // HH*B*N1*2
    float* pred_pos = hist_pos + (size_t)HH * B * N1 * 2;   // B*N1*NP*2
    float* wqkvo_t  = pred_pos + (size_t)B * N1 * NP * 2;   // 4 * F*F
    float* wq_t = wqkvo_t;
    float* wk_t = wqkvo_t + (size_t)F * F;
    float* wv_t = wqkvo_t + (size_t)2 * F * F;
    float* wo_t = wqkvo_t + (size_t)3 * F * F;
    float* wlstm_t  = wqkvo_t + (size_t)4 * F * F;          // 4 * G4*F
    float* ego_wih_t = wlstm_t;
    float* ego_whh_t = wlstm_t + (size_t)G4 * F;
    float* veh_wih_t = wlstm_t + (size_t)2 * G4 * F;
    float* veh_whh_t = wlstm_t + (size_t)3 * G4 * F;

    float* hb[2] = {h0, h1p};
    float* cb[2] = {c0, c1p};

    // ---- init ----
    hipMemsetAsync(h0, 0, (size_t)B * N1 * F * sizeof(float), stream);
    hipMemsetAsync(c0, 0, (size_t)B * N1 * F * sizeof(float), stream);
    k_transpose4<<<4 * F, F, 0, stream>>>(wq, wk, wv, wo, wqkvo_t);
    k_transpose_lstm<<<(4 * G4 * F + 255) / 256, 256, 0, stream>>>(ego_wih, ego_whh,
                                                                   veh_wih, veh_whh, wlstm_t);
    k_lane_tok<<<B * L, 64, 0, stream>>>(lane_input, lane_w1, lane_b1, lane_w2, lane_b2,
                                         lane_to_f, kv);
    k_hist_pos<<<(B * N1 + 255) / 256, 256, 0, stream>>>(input, init_pos, hist_pos, pred_pos);
    k_lane_kv<<<B * 8, 256, 0, stream>>>(kv, wk_t, wv_t, kb, vb);

    int cur = 0;
    for (int step = 0; step < HH + LEN; ++step) {
        int mode = (step < HH) ? 0 : 1;
        int t = (mode == 0) ? step : 0;
        int s = (mode == 0) ? 0 : step - HH;
        k_tok_qkv<<<B * 4, 256, 0, stream>>>(input, hist_pos, hb[cur], pred_pos,
                                             conv_w, conv_b, pos_w, pos_b,
                                             wq_t, wk_t, wv_t, kv, qb, kb, vb, mode, t);
        k_attn<<<B * NH, 64, 0, stream>>>(qb, kb, vb, mask_input, lane_mask, ao);
        k_proj_ln<<<B * 4, 256, 0, stream>>>(ao, kv, wo_t, ln_ego_g, ln_ego_b, ln_g, ln_b, xln);
        k_lstm_pred<<<N1 * 8, 256, 0, stream>>>(xln, ego_wih_t, ego_whh_t, ego_bih, ego_bhh,
                                                veh_wih_t, veh_whh_t, veh_bih, veh_bhh,
                                                hb[cur], cb[cur], hb[1 - cur], cb[1 - cur],
                                                out_ego_w, out_ego_b, out_w, out_b,
                                                pred_pos, out, mode, s);
        cur ^= 1;
    }
}

// Round 7
// 6618.276 us; speedup vs baseline: 1.8164x; 1.3566x over previous
//
#include <hip/hip_runtime.h>
#include <hip/hip_bf16.h>
#include <math.h>

// ---------------- constants (fixed by setup_inputs) ----------------
constexpr int B   = 128;   // batch
constexpr int N1  = 32;    // agents (1 ego + 31 veh)
constexpr int HH  = 20;    // history steps (T-2)
constexpr int L   = 64;    // lanes
constexpr int PTS = 10;    // points per lane
constexpr int F   = 128;   // feature size
constexpr int LF  = 64;    // lane feature
constexpr int NH  = 8;     // heads
constexpr int HD  = 16;    // head dim
constexpr int KVN = 96;    // kv tokens = 32 agents + 64 lanes
constexpr int G4  = 512;   // 4*F lstm gates
constexpr int NP  = 6;     // num preds
constexpr int P6  = 36;    // NP*6
constexpr int LEN = 30;    // len_pred

__device__ __forceinline__ float sigmoidf(float x) { return 1.f / (1.f + expf(-x)); }
__device__ __forceinline__ float dot4(float4 a, float4 b) {
    return a.x * b.x + a.y * b.y + a.z * b.z + a.w * b.w;
}

// ---------------- one-time kernels ----------------

// lane MLP -> lane tokens (kv rows 32..95). One wave per (b,l).
__global__ __launch_bounds__(64) void k_lane_tok(
        const float* __restrict__ lane_input,
        const float* __restrict__ w1, const float* __restrict__ b1,
        const float* __restrict__ w2, const float* __restrict__ b2,
        const float* __restrict__ to_f,
        float* __restrict__ kvbuf) {
    int bl = blockIdx.x; int b = bl / L, l = bl % L;
    int j = threadIdx.x; // 64
    __shared__ float w1s[2 * LF];
    __shared__ float b1s[LF];
    __shared__ float ml[LF];
    w1s[j] = w1[j]; w1s[LF + j] = w1[LF + j]; b1s[j] = b1[j];
    float x0[PTS], x1[PTS];
#pragma unroll
    for (int p = 0; p < PTS; ++p) {
        x0[p] = lane_input[((size_t)(b * L + l) * PTS + p) * 2 + 0];
        x1[p] = lane_input[((size_t)(b * L + l) * PTS + p) * 2 + 1];
    }
    __syncthreads();
    float mp[PTS];
#pragma unroll
    for (int p = 0; p < PTS; ++p) mp[p] = 0.f;
    for (int hh = 0; hh < LF; ++hh) {
        float w10 = w1s[hh], w11 = w1s[LF + hh], b1h = b1s[hh];
        float wv = w2[hh * LF + j];
#pragma unroll
        for (int p = 0; p < PTS; ++p) {
            float h1v = fmaxf(x0[p] * w10 + x1[p] * w11 + b1h, 0.f);
            mp[p] += h1v * wv;
        }
    }
    float b2j = b2[j];
    float m = 0.f;
#pragma unroll
    for (int p = 0; p < PTS; ++p) m += fmaxf(mp[p] + b2j, 0.f);
    ml[j] = m * (1.f / PTS);
    __syncthreads();
    float* outp = kvbuf + ((size_t)(b * KVN) + 32 + l) * F;
    float acc0 = 0.f, acc1 = 0.f;
    for (int j2 = 0; j2 < LF; ++j2) {
        float mv = ml[j2];
        acc0 += mv * to_f[j2 * F + j];
        acc1 += mv * to_f[j2 * F + 64 + j];
    }
    outp[j] = acc0; outp[64 + j] = acc1;
}

// lane K/V: project constant lane tokens once. 8 rows per block.
__global__ __launch_bounds__(256) void k_lane_kv(
        const float* __restrict__ kvbuf,
        const float* __restrict__ wk_t, const float* __restrict__ wv_t,
        float* __restrict__ kb, float* __restrict__ vb) {
    int g = blockIdx.x & 7, b = blockIdx.x >> 3;
    int n0 = 32 + g * 8;
    int tid = threadIdx.x; // 256 = 4 waves
    int w = tid >> 6, j = tid & 63;
    int r0 = (w >> 1) * 4;
    int c = (w & 1) * 64 + j;
    __shared__ float tok[8][F];
    for (int i = tid; i < 8 * F; i += 256) {
        int r = i >> 7, cc = i & 127;
        tok[r][cc] = kvbuf[((size_t)b * KVN + n0 + r) * F + cc];
    }
    __syncthreads();
    float ak[4] = {0, 0, 0, 0}, av[4] = {0, 0, 0, 0};
    for (int k2 = 0; k2 < F; k2 += 4) {
        float4 wkv = *(const float4*)(wk_t + (size_t)c * F + k2);
        float4 wvv = *(const float4*)(wv_t + (size_t)c * F + k2);
#pragma unroll
        for (int r = 0; r < 4; ++r) {
            float4 xv = *(const float4*)&tok[r0 + r][k2];
            ak[r] += dot4(xv, wkv); av[r] += dot4(xv, wvv);
        }
    }
#pragma unroll
    for (int r = 0; r < 4; ++r) {
        int n = n0 + r0 + r;
        kb[((size_t)b * KVN + n) * F + c] = ak[r];
        vb[((size_t)b * KVN + n) * F + c] = av[r];
    }
}

__global__ void k_hist_pos(const float* __restrict__ input,
                           const float* __restrict__ init_pos,
                           float* __restrict__ hist_pos,
                           float* __restrict__ pred_pos) {
    int idx = blockIdx.x * blockDim.x + threadIdx.x;
    if (idx >= B * N1) return;
    float px = init_pos[idx * 2], py = init_pos[idx * 2 + 1];
    int b = idx / N1, n = idx % N1;
    for (int t = 0; t < HH; ++t) {
        const float* ip = input + ((size_t)(t * B + b) * N1 + n) * 2;
        float dl = ip[0], yaw = ip[1];
        px += dl * cosf(yaw);
        py += dl * sinf(yaw);
        float* hp = hist_pos + ((size_t)(t * B + b) * N1 + n) * 2;
        hp[0] = px; hp[1] = py;
    }
#pragma unroll
    for (int p = 0; p < NP; ++p) {
        pred_pos[((size_t)idx * NP + p) * 2 + 0] = px;
        pred_pos[((size_t)idx * NP + p) * 2 + 1] = py;
    }
}

// transpose wq,wk,wv,wo (each F x F, k-major) -> (col, k) layout
__global__ void k_transpose4(const float* __restrict__ w0, const float* __restrict__ w1,
                             const float* __restrict__ w2, const float* __restrict__ w3,
                             float* __restrict__ wt) {
    int m = blockIdx.x >> 7, c = blockIdx.x & 127;
    int k = threadIdx.x; // 128
    const float* src = (m == 0) ? w0 : (m == 1) ? w1 : (m == 2) ? w2 : w3;
    wt[(size_t)m * F * F + (size_t)c * F + k] = src[(size_t)k * F + c];
}

// LSTM weights (G4,F) -> interleaved-gate (k, ci) layout: wt[k][4*f+g] = w[g*128+f][k].
// Gather reads, fully coalesced float4 writes. grid 4*128 blocks x 128 threads.
__global__ void k_transpose_lstm(const float* __restrict__ w0, const float* __restrict__ w1,
                                 const float* __restrict__ w2, const float* __restrict__ w3,
                                 float* __restrict__ wt) {
    int m = blockIdx.x >> 7, k = blockIdx.x & 127;
    int f = threadIdx.x; // 128
    const float* src = (m == 0) ? w0 : (m == 1) ? w1 : (m == 2) ? w2 : w3;
    float4 v;
    v.x = src[(size_t)(0 * 128 + f) * F + k];
    v.y = src[(size_t)(1 * 128 + f) * F + k];
    v.z = src[(size_t)(2 * 128 + f) * F + k];
    v.w = src[(size_t)(3 * 128 + f) * F + k];
    *(float4*)(wt + (size_t)m * G4 * F + (size_t)k * G4 + 4 * f) = v;
}

// ---------------- per-step kernels ----------------

// Kernel A: build agent tokens + q/k/v projections. grid B*4, block 256, 8 rows/block.
__global__ __launch_bounds__(256) void k_tok_qkv(
        const float* __restrict__ input, const float* __restrict__ hist_pos,
        const float* __restrict__ h, const float* __restrict__ pred_pos,
        const float* __restrict__ conv_w, const float* __restrict__ conv_b,
        const float* __restrict__ pos_w, const float* __restrict__ pos_b,
        const float* __restrict__ wq_t, const float* __restrict__ wk_t,
        const float* __restrict__ wv_t,
        float* __restrict__ kvbuf, float* __restrict__ qb,
        float* __restrict__ kb, float* __restrict__ vb,
        int mode, int t) {
    int g = blockIdx.x & 3, b = blockIdx.x >> 2;
    int n0 = g * 8;
    int tid = threadIdx.x;
    int w = tid >> 6, j = tid & 63;
    int r0 = (w >> 1) * 4;
    int c = (w & 1) * 64 + j;
    __shared__ float tok[8][F];
    __shared__ float mpos[8][2];
    if (mode == 1 && tid < 8) {
        const float* pp = pred_pos + ((size_t)(b * N1 + n0 + tid)) * NP * 2;
        float mx = 0.f, my = 0.f;
#pragma unroll
        for (int p = 0; p < NP; ++p) { mx += pp[p * 2]; my += pp[p * 2 + 1]; }
        mpos[tid][0] = mx * (1.f / NP); mpos[tid][1] = my * (1.f / NP);
    }
    __syncthreads();
    for (int i = tid; i < 8 * F; i += 256) {
        int r = i >> 7, cc = i & 127;
        int n = n0 + r;
        float acc;
        if (mode == 0) {
            acc = conv_b[cc];
#pragma unroll
            for (int kt = 0; kt < 3; ++kt) {
                const float* ip = input + ((size_t)((t + kt) * B + b) * N1 + n) * 2;
                acc += ip[0] * conv_w[(cc * 2 + 0) * 3 + kt] + ip[1] * conv_w[(cc * 2 + 1) * 3 + kt];
            }
            const float* hp = hist_pos + ((size_t)(t * B + b) * N1 + n) * 2;
            acc += hp[0] * pos_w[cc] + hp[1] * pos_w[F + cc] + pos_b[cc];
        } else {
            acc = h[((size_t)b * N1 + n) * F + cc]
                + mpos[r][0] * pos_w[cc] + mpos[r][1] * pos_w[F + cc] + pos_b[cc];
        }
        tok[r][cc] = acc;
        kvbuf[((size_t)b * KVN + n) * F + cc] = acc;
    }
    __syncthreads();
    float aq[4] = {0, 0, 0, 0}, ak[4] = {0, 0, 0, 0}, av[4] = {0, 0, 0, 0};
    for (int k2 = 0; k2 < F; k2 += 4) {
        float4 wqv = *(const float4*)(wq_t + (size_t)c * F + k2);
        float4 wkv = *(const float4*)(wk_t + (size_t)c * F + k2);
        float4 wvv = *(const float4*)(wv_t + (size_t)c * F + k2);
#pragma unroll
        for (int r = 0; r < 4; ++r) {
            float4 xv = *(const float4*)&tok[r0 + r][k2];
            aq[r] += dot4(xv, wqv); ak[r] += dot4(xv, wkv); av[r] += dot4(xv, wvv);
        }
    }
#pragma unroll
    for (int r = 0; r < 4; ++r) {
        int n = n0 + r0 + r;
        qb[((size_t)b * N1 + n) * F + c]  = aq[r];
        kb[((size_t)b * KVN + n) * F + c] = ak[r];
        vb[((size_t)b * KVN + n) * F + c] = av[r];
    }
}

// Kernel B1: attention. grid B*2, block 256 (4 waves), wave = one head.
// lane = (qr 0..31, dh 0..1). Two interleaved online-softmax chains.
__global__ __launch_bounds__(256) void k_attn(
        const float* __restrict__ qb, const float* __restrict__ kb,
        const float* __restrict__ vb,
        const float* __restrict__ mask_in, const float* __restrict__ lane_mask,
        float* __restrict__ ao) {
    int hb = blockIdx.x & 1, b = blockIdx.x >> 1;
    int tid = threadIdx.x;
    int w = tid >> 6, t = tid & 63;
    int h = hb * 4 + w;
    int qr = t & 31, dh = t >> 5;
    __shared__ float mk[KVN];
    if (tid < KVN)
        mk[tid] = (tid < N1) ? mask_in[b * N1 + tid] : lane_mask[b * L + (tid - N1)];
    const float* qp = qb + ((size_t)b * N1 + qr) * F + h * HD + dh * 8;
    float4 q0 = *(const float4*)qp, q1 = *(const float4*)(qp + 4);
    __syncthreads();
    const float* kbase = kb + (size_t)b * KVN * F + h * HD + dh * 8;
    const float* vbase = vb + (size_t)b * KVN * F + h * HD + dh * 8;
    float mA = -1e30f, lA = 0.f, mB = -1e30f, lB = 0.f;
    float4 oA0 = {0,0,0,0}, oA1 = {0,0,0,0}, oB0 = {0,0,0,0}, oB1 = {0,0,0,0};
    constexpr int HALF = KVN / 2; // 48
    for (int kc = 0; kc < HALF; ++kc) {
        int ka = kc, kb2 = kc + HALF;
        float4 a0 = *(const float4*)(kbase + (size_t)ka * F);
        float4 a1 = *(const float4*)(kbase + (size_t)ka * F + 4);
        float4 b0 = *(const float4*)(kbase + (size_t)kb2 * F);
        float4 b1 = *(const float4*)(kbase + (size_t)kb2 * F + 4);
        float shA = dot4(q0, a0) + dot4(q1, a1);
        float shB = dot4(q0, b0) + dot4(q1, b1);
        float sA = shA + __shfl_xor(shA, 32, 64);
        float sB = shB + __shfl_xor(shB, 32, 64);
        sA = (mk[ka]  > 0.f) ? sA * 0.25f : -1e9f;
        sB = (mk[kb2] > 0.f) ? sB * 0.25f : -1e9f;
        float mnA = fmaxf(mA, sA), mnB = fmaxf(mB, sB);
        float cA = expf(mA - mnA), cB = expf(mB - mnB);
        float pA = expf(sA - mnA), pB = expf(sB - mnB);
        lA = lA * cA + pA; lB = lB * cB + pB;
        float4 va0 = *(const float4*)(vbase + (size_t)ka * F);
        float4 va1 = *(const float4*)(vbase + (size_t)ka * F + 4);
        float4 vb0 = *(const float4*)(vbase + (size_t)kb2 * F);
        float4 vb1 = *(const float4*)(vbase + (size_t)kb2 * F + 4);
        oA0.x = fmaf(oA0.x, cA, pA * va0.x); oA0.y = fmaf(oA0.y, cA, pA * va0.y);
        oA0.z = fmaf(oA0.z, cA, pA * va0.z); oA0.w = fmaf(oA0.w, cA, pA * va0.w);
        oA1.x = fmaf(oA1.x, cA, pA * va1.x); oA1.y = fmaf(oA1.y, cA, pA * va1.y);
        oA1.z = fmaf(oA1.z, cA, pA * va1.z); oA1.w = fmaf(oA1.w, cA, pA * va1.w);
        oB0.x = fmaf(oB0.x, cB, pB * vb0.x); oB0.y = fmaf(oB0.y, cB, pB * vb0.y);
        oB0.z = fmaf(oB0.z, cB, pB * vb0.z); oB0.w = fmaf(oB0.w, cB, pB * vb0.w);
        oB1.x = fmaf(oB1.x, cB, pB * vb1.x); oB1.y = fmaf(oB1.y, cB, pB * vb1.y);
        oB1.z = fmaf(oB1.z, cB, pB * vb1.z); oB1.w = fmaf(oB1.w, cB, pB * vb1.w);
        mA = mnA; mB = mnB;
    }
    float mn = fmaxf(mA, mB);
    float fa = expf(mA - mn), fb = expf(mB - mn);
    float l = lA * fa + lB * fb;
    float inv = 1.f / l;
    float ia = fa * inv, ib = fb * inv;
    float4 o0, o1;
    o0.x = oA0.x * ia + oB0.x * ib; o0.y = oA0.y * ia + oB0.y * ib;
    o0.z = oA0.z * ia + oB0.z * ib; o0.w = oA0.w * ia + oB0.w * ib;
    o1.x = oA1.x * ia + oB1.x * ib; o1.y = oA1.y * ia + oB1.y * ib;
    o1.z = oA1.z * ia + oB1.z * ib; o1.w = oA1.w * ia + oB1.w * ib;
    float* op = ao + ((size_t)b * N1 + qr) * F + h * HD + dh * 8;
    *(float4*)op = o0; *(float4*)(op + 4) = o1;
}

// Kernel B2: out-proj + residual + layernorm. grid B*4, block 256, 8 rows/block.
__global__ __launch_bounds__(256) void k_proj_ln(
        const float* __restrict__ ao, const float* __restrict__ kvbuf,
        const float* __restrict__ wo_t,
        const float* __restrict__ ln_ego_g, const float* __restrict__ ln_ego_b,
        const float* __restrict__ ln_g, const float* __restrict__ ln_b,
        float* __restrict__ xln) {
    int gq = blockIdx.x & 3, b = blockIdx.x >> 2;
    int n0 = gq * 8;
    int tid = threadIdx.x; // 256
    int w = tid >> 6, j = tid & 63;
    int r0 = w * 2;
    __shared__ float as[8][F];
    for (int i = tid; i < 8 * F; i += 256) {
        int r = i >> 7, cc = i & 127;
        as[r][cc] = ao[((size_t)b * N1 + n0 + r) * F + cc];
    }
    __syncthreads();
    float acc[2][2] = {{0, 0}, {0, 0}};
    for (int k2 = 0; k2 < F; k2 += 4) {
        float4 w0 = *(const float4*)(wo_t + (size_t)j * F + k2);
        float4 w1 = *(const float4*)(wo_t + (size_t)(j + 64) * F + k2);
#pragma unroll
        for (int r = 0; r < 2; ++r) {
            float4 av4 = *(const float4*)&as[r0 + r][k2];
            acc[r][0] += dot4(av4, w0);
            acc[r][1] += dot4(av4, w1);
        }
    }
#pragma unroll
    for (int r = 0; r < 2; ++r) {
        int n = n0 + r0 + r;
        size_t base = ((size_t)b * KVN + n) * F;
        float x0 = kvbuf[base + j] + acc[r][0];
        float x1 = kvbuf[base + j + 64] + acc[r][1];
        float s1 = x0 + x1, s2 = x0 * x0 + x1 * x1;
#pragma unroll
        for (int off = 32; off > 0; off >>= 1) {
            s1 += __shfl_xor(s1, off, 64);
            s2 += __shfl_xor(s2, off, 64);
        }
        float mean = s1 * (1.f / F);
        float var = s2 * (1.f / F) - mean * mean;
        float rstd = rsqrtf(var + 1e-5f);
        const float* gg = (n == 0) ? ln_ego_g : ln_g;
        const float* bbv = (n == 0) ? ln_ego_b : ln_b;
        size_t ob = ((size_t)b * N1 + n) * F;
        xln[ob + j]      = (x0 - mean) * rstd * gg[j] + bbv[j];
        xln[ob + j + 64] = (x1 - mean) * rstd * gg[j + 64] + bbv[j + 64];
    }
}

// ---- LSTM helpers: interleaved-gate layout, double-buffered weight stream ----
__device__ __forceinline__ void lstm_load_w(const float* __restrict__ wi,
                                            const float* __restrict__ wh,
                                            int k4, int ln, float4* wbuf) {
#pragma unroll
    for (int kk = 0; kk < 4; ++kk) {
        const float* pi = wi + (size_t)(k4 + kk) * G4 + 4 * ln;
        const float* ph = wh + (size_t)(k4 + kk) * G4 + 4 * ln;
        wbuf[kk * 4 + 0] = *(const float4*)pi;
        wbuf[kk * 4 + 1] = *(const float4*)(pi + 256);
        wbuf[kk * 4 + 2] = *(const float4*)ph;
        wbuf[kk * 4 + 3] = *(const float4*)(ph + 256);
    }
}

__device__ __forceinline__ void lstm_fma(int k4, int r0,
                                         const float (*xs)[F], const float (*hs)[F],
                                         const float4* wbuf, float (*acc)[8]) {
    float4 xv[4], hv[4];
#pragma unroll
    for (int r = 0; r < 4; ++r) {
        xv[r] = *(const float4*)&xs[r0 + r][k4];
        hv[r] = *(const float4*)&hs[r0 + r][k4];
    }
#pragma unroll
    for (int kk = 0; kk < 4; ++kk) {
        float4 wa0 = wbuf[kk * 4 + 0], wa1 = wbuf[kk * 4 + 1];
        float4 wb0 = wbuf[kk * 4 + 2], wb1 = wbuf[kk * 4 + 3];
#pragma unroll
        for (int r = 0; r < 4; ++r) {
            float x = ((const float*)&xv[r])[kk];
            float hc = ((const float*)&hv[r])[kk];
            acc[r][0] += x * wa0.x + hc * wb0.x;
            acc[r][1] += x * wa0.y + hc * wb0.y;
            acc[r][2] += x * wa0.z + hc * wb0.z;
            acc[r][3] += x * wa0.w + hc * wb0.w;
            acc[r][4] += x * wa1.x + hc * wb1.x;
            acc[r][5] += x * wa1.y + hc * wb1.y;
            acc[r][6] += x * wa1.z + hc * wb1.z;
            acc[r][7] += x * wa1.w + hc * wb1.w;
        }
    }
}

// Kernel C: LSTM cell + (pred mode) output head + pos update + y.
// grid N1*8 = 256 blocks, block 256 (4 waves), 16 batch rows of one agent n.
// Weights in interleaved (k, 4f+g) layout: lane ln owns all 4 gates of
// features ln and 64+ln -> no gate exchange; coalesced dword c/h writes.
__global__ __launch_bounds__(256, 1) void k_lstm_pred(
        const float* __restrict__ xln,
        const float* __restrict__ ego_wih_t, const float* __restrict__ ego_whh_t,
        const float* __restrict__ ego_bih, const float* __restrict__ ego_bhh,
        const float* __restrict__ veh_wih_t, const float* __restrict__ veh_whh_t,
        const float* __restrict__ veh_bih, const float* __restrict__ veh_bhh,
        const float* __restrict__ h_in, const float* __restrict__ c_in,
        float* __restrict__ h_out, float* __restrict__ c_out,
        const float* __restrict__ out_ego_w, const float* __restrict__ out_ego_b,
        const float* __restrict__ out_w, const float* __restrict__ out_b,
        float* __restrict__ pred_pos, float* __restrict__ out,
        int mode, int step) {
    int n = blockIdx.x >> 3, bg = blockIdx.x & 7;
    int b0 = bg * 16;
    int tid = threadIdx.x; // 256
    int w = tid >> 6, ln = tid & 63;
    int r0 = w * 4;
    const float *wih, *whh, *bih, *bhh;
    if (n == 0) { wih = ego_wih_t; whh = ego_whh_t; bih = ego_bih; bhh = ego_bhh; }
    else        { wih = veh_wih_t; whh = veh_whh_t; bih = veh_bih; bhh = veh_bhh; }
    __shared__ float xs[16][F];   // 8 KB
    __shared__ float hs[16][F];   // 8 KB
    __shared__ float h2s[16][F];  // 8 KB (pred head)
    __shared__ float os[16][P6];
    for (int i = tid; i < 16 * (F / 4); i += 256) {
        int r = i >> 5, c4 = i & 31;
        size_t bn = (size_t)(b0 + r) * N1 + n;
        *(float4*)&xs[r][c4 * 4] = *(const float4*)(xln  + bn * F + c4 * 4);
        *(float4*)&hs[r][c4 * 4] = *(const float4*)(h_in + bn * F + c4 * 4);
    }
    __syncthreads();
    // acc[r][q]: q 0..3 = gates i,f,g,o of feature ln; q 4..7 = feature 64+ln
    float acc[4][8];
    {
        float bs[8];
#pragma unroll
        for (int g = 0; g < 4; ++g) {
            bs[g]     = bih[g * 128 + ln]      + bhh[g * 128 + ln];
            bs[4 + g] = bih[g * 128 + 64 + ln] + bhh[g * 128 + 64 + ln];
        }
#pragma unroll
        for (int r = 0; r < 4; ++r)
#pragma unroll
            for (int q = 0; q < 8; ++q) acc[r][q] = bs[q];
    }
    float4 wc[16], wn[16];
    lstm_load_w(wih, whh, 0, ln, wc);
    for (int k4 = 0; k4 < F; k4 += 8) {
        lstm_load_w(wih, whh, k4 + 4, ln, wn);
        lstm_fma(k4, r0, xs, hs, wc, acc);
        if (k4 + 8 < F) lstm_load_w(wih, whh, k4 + 8, ln, wc);
        lstm_fma(k4 + 4, r0, xs, hs, wn, acc);
    }
    // epilogue: lane finalizes features ln and 64+ln for its 4 rows
#pragma unroll
    for (int r = 0; r < 4; ++r) {
        int row = r0 + r;
        size_t bn = (size_t)(b0 + row) * N1 + n;
        float ca = c_in[bn * F + ln];
        float cb2 = c_in[bn * F + 64 + ln];
        float c2a = sigmoidf(acc[r][1]) * ca + sigmoidf(acc[r][0]) * tanhf(acc[r][2]);
        float h2a = sigmoidf(acc[r][3]) * tanhf(c2a);
        float c2b = sigmoidf(acc[r][5]) * cb2 + sigmoidf(acc[r][4]) * tanhf(acc[r][6]);
        float h2b = sigmoidf(acc[r][7]) * tanhf(c2b);
        c_out[bn * F + ln] = c2a;      h_out[bn * F + ln] = h2a;
        c_out[bn * F + 64 + ln] = c2b; h_out[bn * F + 64 + ln] = h2b;
        h2s[row][ln] = h2a;            h2s[row][64 + ln] = h2b;
    }
    if (mode == 1) {
        const float* W  = (n == 0) ? out_ego_w : out_w;
        const float* bb = (n == 0) ? out_ego_b : out_b;
        __syncthreads();
        for (int i = tid; i < 16 * P6; i += 256) {
            int r = i / P6, jo = i % P6;
            float a = bb[jo];
            for (int k4 = 0; k4 < F; k4 += 4) {
                float4 hx = *(const float4*)&h2s[r][k4];
                a += hx.x * W[(k4    ) * P6 + jo] + hx.y * W[(k4 + 1) * P6 + jo]
                   + hx.z * W[(k4 + 2) * P6 + jo] + hx.w * W[(k4 + 3) * P6 + jo];
            }
            os[r][jo] = a;
        }
        __syncthreads();
        if (tid < 16 * NP) {
            int r = tid / NP, p = tid % NP;
            size_t bn = (size_t)(b0 + r) * N1 + n;
            float dl = os[r][p * 6 + 0], yaw = os[r][p * 6 + 1];
            float* pp = pred_pos + (bn * NP + p) * 2;
            float px = pp[0] + dl * cosf(yaw);
            float py = pp[1] + dl * sinf(yaw);
            pp[0] = px; pp[1] = py;
            float* y = out + (size_t)step * B * N1 * P6 + (bn * NP + p) * 6;
            y[0] = px; y[1] = py;
            y[2] = os[r][p * 6 + 2]; y[3] = os[r][p * 6 + 3];
            y[4] = os[r][p * 6 + 4]; y[5] = os[r][p * 6 + 5];
        }
    }
}

// ---------------- launcher ----------------
extern "C" void kernel_launch(void* const* d_in, const int* in_sizes, int n_in,
                              void* d_out, int out_size, void* d_ws, size_t ws_size,
                              hipStream_t stream) {
    const float* input      = (const float*)d_in[0];
    const float* init_pos   = (const float*)d_in[1];
    const float* lane_input = (const float*)d_in[2];
    const float* mask_input = (const float*)d_in[3];
    const float* lane_mask  = (const float*)d_in[4];
    const float* conv_w     = (const float*)d_in[5];
    const float* conv_b     = (const float*)d_in[6];
    const float* pos_w      = (const float*)d_in[7];
    const float* pos_b      = (const float*)d_in[8];
    const float* lane_w1    = (const float*)d_in[9];
    const float* lane_b1    = (const float*)d_in[10];
    const float* lane_w2    = (const float*)d_in[11];
    const float* lane_b2    = (const float*)d_in[12];
    const float* lane_to_f  = (const float*)d_in[13];
    const float* wq         = (const float*)d_in[14];
    const float* wk         = (const float*)d_in[15];
    const float* wv         = (const float*)d_in[16];
    const float* wo         = (const float*)d_in[17];
    const float* ln_ego_g   = (const float*)d_in[18];
    const float* ln_ego_b   = (const float*)d_in[19];
    const float* ln_g       = (const float*)d_in[20];
    const float* ln_b       = (const float*)d_in[21];
    const float* ego_wih    = (const float*)d_in[22];
    const float* ego_whh    = (const float*)d_in[23];
    const float* ego_bih    = (const float*)d_in[24];
    const float* ego_bhh    = (const float*)d_in[25];
    const float* veh_wih    = (const float*)d_in[26];
    const float* veh_whh    = (const float*)d_in[27];
    const float* veh_bih    = (const float*)d_in[28];
    const float* veh_bhh    = (const float*)d_in[29];
    const float* out_ego_w  = (const float*)d_in[30];
    const float* out_ego_b  = (const float*)d_in[31];
    const float* out_w      = (const float*)d_in[32];
    const float* out_b      = (const float*)d_in[33];

    float* out = (float*)d_out;
    float* ws = (float*)d_ws;

    // workspace layout (floats)
    float* kv       = ws;                        // B*KVN*F
    float* qb       = kv + (size_t)B * KVN * F;  // B*N1*F
    float* kb       = qb + (size_t)B * N1 * F;   // B*KVN*F
    float* vb       = kb + (size_t)B * KVN * F;  // B*KVN*F
    float* ao       = vb + (size_t)B * KVN * F;  // B*N1*F
    float* xln      = ao + (size_t)B * N1 * F;   // B*N1*F
    float* h0       = xln + (size_t)B * N1 * F;
    float* h1p      = h0 + (size_t)B * N1 * F;
    float* c0       = h1p + (size_t)B * N1 * F;
    float* c1p      = c0 + (size_t)B * N1 * F;
    float* hist_pos = c1p + (size_t)B * N1 * F;             // HH*B*N1*2
    float* pred_pos = hist_pos + (size_t)HH * B * N1 * 2;   // B*N1*NP*2
    float* wqkvo_t  = pred_pos + (size_t)B * N1 * NP * 2;   // 4 * F*F
    float* wq_t = wqkvo_t;
    float* wk_t = wqkvo_t + (size_t)F * F;
    float* wv_t = wqkvo_t + (size_t)2 * F * F;
    float* wo_t = wqkvo_t + (size_t)3 * F * F;
    float* wlstm_t  = wqkvo_t + (size_t)4 * F * F;          // 4 * G4*F
    float* ego_wih_t = wlstm_t;
    float* ego_whh_t = wlstm_t + (size_t)G4 * F;
    float* veh_wih_t = wlstm_t + (size_t)2 * G4 * F;
    float* veh_whh_t = wlstm_t + (size_t)3 * G4 * F;

    float* hb[2] = {h0, h1p};
    float* cb[2] = {c0, c1p};

    // ---- init ----
    hipMemsetAsync(h0, 0, (size_t)B * N1 * F * sizeof(float), stream);
    hipMemsetAsync(c0, 0, (size_t)B * N1 * F * sizeof(float), stream);
    k_transpose4<<<4 * F, F, 0, stream>>>(wq, wk, wv, wo, wqkvo_t);
    k_transpose_lstm<<<4 * F, F, 0, stream>>>(ego_wih, ego_whh, veh_wih, veh_whh, wlstm_t);
    k_lane_tok<<<B * L, 64, 0, stream>>>(lane_input, lane_w1, lane_b1, lane_w2, lane_b2,
                                         lane_to_f, kv);
    k_hist_pos<<<(B * N1 + 255) / 256, 256, 0, stream>>>(input, init_pos, hist_pos, pred_pos);
    k_lane_kv<<<B * 8, 256, 0, stream>>>(kv, wk_t, wv_t, kb, vb);

    int cur = 0;
    for (int step = 0; step < HH + LEN; ++step) {
        int mode = (step < HH) ? 0 : 1;
        int t = (mode == 0) ? step : 0;
        int s = (mode == 0) ? 0 : step - HH;
        k_tok_qkv<<<B * 4, 256, 0, stream>>>(input, hist_pos, hb[cur], pred_pos,
                                             conv_w, conv_b, pos_w, pos_b,
                                             wq_t, wk_t, wv_t, kv, qb, kb, vb, mode, t);
        k_attn<<<B * 2, 256, 0, stream>>>(qb, kb, vb, mask_input, lane_mask, ao);
        k_proj_ln<<<B * 4, 256, 0, stream>>>(ao, kv, wo_t, ln_ego_g, ln_ego_b, ln_g, ln_b, xln);
        k_lstm_pred<<<N1 * 8, 256, 0, stream>>>(xln, ego_wih_t, ego_whh_t, ego_bih, ego_bhh,
                                                veh_wih_t, veh_whh_t, veh_bih, veh_bhh,
                                                hb[cur], cb[cur], hb[1 - cur], cb[1 - cur],
                                                out_ego_w, out_ego_b, out_w, out_b,
                                                pred_pos, out, mode, s);
        cur ^= 1;
    }
}

// Round 8
// 6182.732 us; speedup vs baseline: 1.9444x; 1.0704x over previous
//
#include <hip/hip_runtime.h>
#include <hip/hip_bf16.h>
#include <math.h>

// ---------------- constants (fixed by setup_inputs) ----------------
constexpr int B   = 128;   // batch
constexpr int N1  = 32;    // agents (1 ego + 31 veh)
constexpr int HH  = 20;    // history steps (T-2)
constexpr int L   = 64;    // lanes
constexpr int PTS = 10;    // points per lane
constexpr int F   = 128;   // feature size
constexpr int LF  = 64;    // lane feature
constexpr int NH  = 8;     // heads
constexpr int HD  = 16;    // head dim
constexpr int KVN = 96;    // kv tokens = 32 agents + 64 lanes
constexpr int G4  = 512;   // 4*F lstm gates
constexpr int NP  = 6;     // num preds
constexpr int P6  = 36;    // NP*6
constexpr int LEN = 30;    // len_pred

__device__ __forceinline__ float sigmoidf(float x) { return 1.f / (1.f + expf(-x)); }
__device__ __forceinline__ float dot4(float4 a, float4 b) {
    return a.x * b.x + a.y * b.y + a.z * b.z + a.w * b.w;
}

// ---------------- one-time kernels ----------------

// lane MLP -> lane tokens (kv rows 32..95). One wave per (b,l).
__global__ __launch_bounds__(64) void k_lane_tok(
        const float* __restrict__ lane_input,
        const float* __restrict__ w1, const float* __restrict__ b1,
        const float* __restrict__ w2, const float* __restrict__ b2,
        const float* __restrict__ to_f,
        float* __restrict__ kvbuf) {
    int bl = blockIdx.x; int b = bl / L, l = bl % L;
    int j = threadIdx.x; // 64
    __shared__ float w1s[2 * LF];
    __shared__ float b1s[LF];
    __shared__ float ml[LF];
    w1s[j] = w1[j]; w1s[LF + j] = w1[LF + j]; b1s[j] = b1[j];
    float x0[PTS], x1[PTS];
#pragma unroll
    for (int p = 0; p < PTS; ++p) {
        x0[p] = lane_input[((size_t)(b * L + l) * PTS + p) * 2 + 0];
        x1[p] = lane_input[((size_t)(b * L + l) * PTS + p) * 2 + 1];
    }
    __syncthreads();
    float mp[PTS];
#pragma unroll
    for (int p = 0; p < PTS; ++p) mp[p] = 0.f;
    for (int hh = 0; hh < LF; ++hh) {
        float w10 = w1s[hh], w11 = w1s[LF + hh], b1h = b1s[hh];
        float wv = w2[hh * LF + j];
#pragma unroll
        for (int p = 0; p < PTS; ++p) {
            float h1v = fmaxf(x0[p] * w10 + x1[p] * w11 + b1h, 0.f);
            mp[p] += h1v * wv;
        }
    }
    float b2j = b2[j];
    float m = 0.f;
#pragma unroll
    for (int p = 0; p < PTS; ++p) m += fmaxf(mp[p] + b2j, 0.f);
    ml[j] = m * (1.f / PTS);
    __syncthreads();
    float* outp = kvbuf + ((size_t)(b * KVN) + 32 + l) * F;
    float acc0 = 0.f, acc1 = 0.f;
    for (int j2 = 0; j2 < LF; ++j2) {
        float mv = ml[j2];
        acc0 += mv * to_f[j2 * F + j];
        acc1 += mv * to_f[j2 * F + 64 + j];
    }
    outp[j] = acc0; outp[64 + j] = acc1;
}

// lane K/V: project constant lane tokens once. 8 rows per block.
__global__ __launch_bounds__(256) void k_lane_kv(
        const float* __restrict__ kvbuf,
        const float* __restrict__ wk_t, const float* __restrict__ wv_t,
        float* __restrict__ kb, float* __restrict__ vb) {
    int g = blockIdx.x & 7, b = blockIdx.x >> 3;
    int n0 = 32 + g * 8;
    int tid = threadIdx.x; // 256 = 4 waves
    int w = tid >> 6, j = tid & 63;
    int r0 = (w >> 1) * 4;
    int c = (w & 1) * 64 + j;
    __shared__ float tok[8][F];
    for (int i = tid; i < 8 * F; i += 256) {
        int r = i >> 7, cc = i & 127;
        tok[r][cc] = kvbuf[((size_t)b * KVN + n0 + r) * F + cc];
    }
    __syncthreads();
    float ak[4] = {0, 0, 0, 0}, av[4] = {0, 0, 0, 0};
    for (int k2 = 0; k2 < F; k2 += 4) {
        float4 wkv = *(const float4*)(wk_t + (size_t)c * F + k2);
        float4 wvv = *(const float4*)(wv_t + (size_t)c * F + k2);
#pragma unroll
        for (int r = 0; r < 4; ++r) {
            float4 xv = *(const float4*)&tok[r0 + r][k2];
            ak[r] += dot4(xv, wkv); av[r] += dot4(xv, wvv);
        }
    }
#pragma unroll
    for (int r = 0; r < 4; ++r) {
        int n = n0 + r0 + r;
        kb[((size_t)b * KVN + n) * F + c] = ak[r];
        vb[((size_t)b * KVN + n) * F + c] = av[r];
    }
}

__global__ void k_hist_pos(const float* __restrict__ input,
                           const float* __restrict__ init_pos,
                           float* __restrict__ hist_pos,
                           float* __restrict__ pred_pos) {
    int idx = blockIdx.x * blockDim.x + threadIdx.x;
    if (idx >= B * N1) return;
    float px = init_pos[idx * 2], py = init_pos[idx * 2 + 1];
    int b = idx / N1, n = idx % N1;
    for (int t = 0; t < HH; ++t) {
        const float* ip = input + ((size_t)(t * B + b) * N1 + n) * 2;
        float dl = ip[0], yaw = ip[1];
        px += dl * cosf(yaw);
        py += dl * sinf(yaw);
        float* hp = hist_pos + ((size_t)(t * B + b) * N1 + n) * 2;
        hp[0] = px; hp[1] = py;
    }
#pragma unroll
    for (int p = 0; p < NP; ++p) {
        pred_pos[((size_t)idx * NP + p) * 2 + 0] = px;
        pred_pos[((size_t)idx * NP + p) * 2 + 1] = py;
    }
}

// transpose wq,wk,wv,wo (each F x F, k-major) -> (col, k) layout
__global__ void k_transpose4(const float* __restrict__ w0, const float* __restrict__ w1,
                             const float* __restrict__ w2, const float* __restrict__ w3,
                             float* __restrict__ wt) {
    int m = blockIdx.x >> 7, c = blockIdx.x & 127;
    int k = threadIdx.x; // 128
    const float* src = (m == 0) ? w0 : (m == 1) ? w1 : (m == 2) ? w2 : w3;
    wt[(size_t)m * F * F + (size_t)c * F + k] = src[(size_t)k * F + c];
}

// LSTM weights (G4,F) -> interleaved-gate (k, ci) layout: wt[k][4*f+g] = w[g*128+f][k].
__global__ void k_transpose_lstm(const float* __restrict__ w0, const float* __restrict__ w1,
                                 const float* __restrict__ w2, const float* __restrict__ w3,
                                 float* __restrict__ wt) {
    int m = blockIdx.x >> 7, k = blockIdx.x & 127;
    int f = threadIdx.x; // 128
    const float* src = (m == 0) ? w0 : (m == 1) ? w1 : (m == 2) ? w2 : w3;
    float4 v;
    v.x = src[(size_t)(0 * 128 + f) * F + k];
    v.y = src[(size_t)(1 * 128 + f) * F + k];
    v.z = src[(size_t)(2 * 128 + f) * F + k];
    v.w = src[(size_t)(3 * 128 + f) * F + k];
    *(float4*)(wt + (size_t)m * G4 * F + (size_t)k * G4 + 4 * f) = v;
}

// interleaved bias: bsum[m][4f+g] = bih[g*128+f] + bhh[g*128+f]
__global__ void k_prep_bias(const float* __restrict__ bih_e, const float* __restrict__ bhh_e,
                            const float* __restrict__ bih_v, const float* __restrict__ bhh_v,
                            float* __restrict__ bsum) {
    int m = blockIdx.x; int ci = threadIdx.x; // grid 2, block 512
    int f = ci >> 2, g = ci & 3;
    const float* bi = m ? bih_v : bih_e;
    const float* bh = m ? bhh_v : bhh_e;
    bsum[m * G4 + ci] = bi[g * 128 + f] + bh[g * 128 + f];
}

// ---------------- per-step kernels ----------------

// Kernel A: build agent tokens + q/k/v projections. grid B*4, block 256, 8 rows/block.
__global__ __launch_bounds__(256) void k_tok_qkv(
        const float* __restrict__ input, const float* __restrict__ hist_pos,
        const float* __restrict__ h, const float* __restrict__ pred_pos,
        const float* __restrict__ conv_w, const float* __restrict__ conv_b,
        const float* __restrict__ pos_w, const float* __restrict__ pos_b,
        const float* __restrict__ wq_t, const float* __restrict__ wk_t,
        const float* __restrict__ wv_t,
        float* __restrict__ kvbuf, float* __restrict__ qb,
        float* __restrict__ kb, float* __restrict__ vb,
        int mode, int t) {
    int g = blockIdx.x & 3, b = blockIdx.x >> 2;
    int n0 = g * 8;
    int tid = threadIdx.x;
    int w = tid >> 6, j = tid & 63;
    int r0 = (w >> 1) * 4;
    int c = (w & 1) * 64 + j;
    __shared__ float tok[8][F];
    __shared__ float mpos[8][2];
    if (mode == 1 && tid < 8) {
        const float* pp = pred_pos + ((size_t)(b * N1 + n0 + tid)) * NP * 2;
        float mx = 0.f, my = 0.f;
#pragma unroll
        for (int p = 0; p < NP; ++p) { mx += pp[p * 2]; my += pp[p * 2 + 1]; }
        mpos[tid][0] = mx * (1.f / NP); mpos[tid][1] = my * (1.f / NP);
    }
    __syncthreads();
    for (int i = tid; i < 8 * F; i += 256) {
        int r = i >> 7, cc = i & 127;
        int n = n0 + r;
        float acc;
        if (mode == 0) {
            acc = conv_b[cc];
#pragma unroll
            for (int kt = 0; kt < 3; ++kt) {
                const float* ip = input + ((size_t)((t + kt) * B + b) * N1 + n) * 2;
                acc += ip[0] * conv_w[(cc * 2 + 0) * 3 + kt] + ip[1] * conv_w[(cc * 2 + 1) * 3 + kt];
            }
            const float* hp = hist_pos + ((size_t)(t * B + b) * N1 + n) * 2;
            acc += hp[0] * pos_w[cc] + hp[1] * pos_w[F + cc] + pos_b[cc];
        } else {
            acc = h[((size_t)b * N1 + n) * F + cc]
                + mpos[r][0] * pos_w[cc] + mpos[r][1] * pos_w[F + cc] + pos_b[cc];
        }
        tok[r][cc] = acc;
        kvbuf[((size_t)b * KVN + n) * F + cc] = acc;
    }
    __syncthreads();
    float aq[4] = {0, 0, 0, 0}, ak[4] = {0, 0, 0, 0}, av[4] = {0, 0, 0, 0};
    for (int k2 = 0; k2 < F; k2 += 4) {
        float4 wqv = *(const float4*)(wq_t + (size_t)c * F + k2);
        float4 wkv = *(const float4*)(wk_t + (size_t)c * F + k2);
        float4 wvv = *(const float4*)(wv_t + (size_t)c * F + k2);
#pragma unroll
        for (int r = 0; r < 4; ++r) {
            float4 xv = *(const float4*)&tok[r0 + r][k2];
            aq[r] += dot4(xv, wqv); ak[r] += dot4(xv, wkv); av[r] += dot4(xv, wvv);
        }
    }
#pragma unroll
    for (int r = 0; r < 4; ++r) {
        int n = n0 + r0 + r;
        qb[((size_t)b * N1 + n) * F + c]  = aq[r];
        kb[((size_t)b * KVN + n) * F + c] = ak[r];
        vb[((size_t)b * KVN + n) * F + c] = av[r];
    }
}

// Kernel B: attention. grid B*2, block 256 (4 waves), wave = one head.
__global__ __launch_bounds__(256) void k_attn(
        const float* __restrict__ qb, const float* __restrict__ kb,
        const float* __restrict__ vb,
        const float* __restrict__ mask_in, const float* __restrict__ lane_mask,
        float* __restrict__ ao) {
    int hb = blockIdx.x & 1, b = blockIdx.x >> 1;
    int tid = threadIdx.x;
    int w = tid >> 6, t = tid & 63;
    int h = hb * 4 + w;
    int qr = t & 31, dh = t >> 5;
    __shared__ float mk[KVN];
    if (tid < KVN)
        mk[tid] = (tid < N1) ? mask_in[b * N1 + tid] : lane_mask[b * L + (tid - N1)];
    const float* qp = qb + ((size_t)b * N1 + qr) * F + h * HD + dh * 8;
    float4 q0 = *(const float4*)qp, q1 = *(const float4*)(qp + 4);
    __syncthreads();
    const float* kbase = kb + (size_t)b * KVN * F + h * HD + dh * 8;
    const float* vbase = vb + (size_t)b * KVN * F + h * HD + dh * 8;
    float mA = -1e30f, lA = 0.f, mB = -1e30f, lB = 0.f;
    float4 oA0 = {0,0,0,0}, oA1 = {0,0,0,0}, oB0 = {0,0,0,0}, oB1 = {0,0,0,0};
    constexpr int HALF = KVN / 2; // 48
    for (int kc = 0; kc < HALF; ++kc) {
        int ka = kc, kb2 = kc + HALF;
        float4 a0 = *(const float4*)(kbase + (size_t)ka * F);
        float4 a1 = *(const float4*)(kbase + (size_t)ka * F + 4);
        float4 b0 = *(const float4*)(kbase + (size_t)kb2 * F);
        float4 b1 = *(const float4*)(kbase + (size_t)kb2 * F + 4);
        float shA = dot4(q0, a0) + dot4(q1, a1);
        float shB = dot4(q0, b0) + dot4(q1, b1);
        float sA = shA + __shfl_xor(shA, 32, 64);
        float sB = shB + __shfl_xor(shB, 32, 64);
        sA = (mk[ka]  > 0.f) ? sA * 0.25f : -1e9f;
        sB = (mk[kb2] > 0.f) ? sB * 0.25f : -1e9f;
        float mnA = fmaxf(mA, sA), mnB = fmaxf(mB, sB);
        float cA = expf(mA - mnA), cB = expf(mB - mnB);
        float pA = expf(sA - mnA), pB = expf(sB - mnB);
        lA = lA * cA + pA; lB = lB * cB + pB;
        float4 va0 = *(const float4*)(vbase + (size_t)ka * F);
        float4 va1 = *(const float4*)(vbase + (size_t)ka * F + 4);
        float4 vb0 = *(const float4*)(vbase + (size_t)kb2 * F);
        float4 vb1 = *(const float4*)(vbase + (size_t)kb2 * F + 4);
        oA0.x = fmaf(oA0.x, cA, pA * va0.x); oA0.y = fmaf(oA0.y, cA, pA * va0.y);
        oA0.z = fmaf(oA0.z, cA, pA * va0.z); oA0.w = fmaf(oA0.w, cA, pA * va0.w);
        oA1.x = fmaf(oA1.x, cA, pA * va1.x); oA1.y = fmaf(oA1.y, cA, pA * va1.y);
        oA1.z = fmaf(oA1.z, cA, pA * va1.z); oA1.w = fmaf(oA1.w, cA, pA * va1.w);
        oB0.x = fmaf(oB0.x, cB, pB * vb0.x); oB0.y = fmaf(oB0.y, cB, pB * vb0.y);
        oB0.z = fmaf(oB0.z, cB, pB * vb0.z); oB0.w = fmaf(oB0.w, cB, pB * vb0.w);
        oB1.x = fmaf(oB1.x, cB, pB * vb1.x); oB1.y = fmaf(oB1.y, cB, pB * vb1.y);
        oB1.z = fmaf(oB1.z, cB, pB * vb1.z); oB1.w = fmaf(oB1.w, cB, pB * vb1.w);
        mA = mnA; mB = mnB;
    }
    float mn = fmaxf(mA, mB);
    float fa = expf(mA - mn), fb = expf(mB - mn);
    float l = lA * fa + lB * fb;
    float inv = 1.f / l;
    float ia = fa * inv, ib = fb * inv;
    float4 o0, o1;
    o0.x = oA0.x * ia + oB0.x * ib; o0.y = oA0.y * ia + oB0.y * ib;
    o0.z = oA0.z * ia + oB0.z * ib; o0.w = oA0.w * ia + oB0.w * ib;
    o1.x = oA1.x * ia + oB1.x * ib; o1.y = oA1.y * ia + oB1.y * ib;
    o1.z = oA1.z * ia + oB1.z * ib; o1.w = oA1.w * ia + oB1.w * ib;
    float* op = ao + ((size_t)b * N1 + qr) * F + h * HD + dh * 8;
    *(float4*)op = o0; *(float4*)(op + 4) = o1;
}

// ---- fused proj+LN+LSTM inner FMA: lane owns 8 interleaved cols at 8*j ----
__device__ __forceinline__ void lstm_fma4(const float (*xs)[F], int k4,
                                          const float4* wb, float (*acc)[8]) {
#pragma unroll
    for (int r = 0; r < 8; ++r) {
        float4 xv = *(const float4*)&xs[r][k4];
        const float* xf = (const float*)&xv;
#pragma unroll
        for (int kk = 0; kk < 4; ++kk) {
            float x = xf[kk];
            float4 wA = wb[kk * 2], wB = wb[kk * 2 + 1];
            acc[r][0] += x * wA.x; acc[r][1] += x * wA.y;
            acc[r][2] += x * wA.z; acc[r][3] += x * wA.w;
            acc[r][4] += x * wB.x; acc[r][5] += x * wB.y;
            acc[r][6] += x * wB.z; acc[r][7] += x * wB.w;
        }
    }
}

// Kernel C: out-proj + residual + LN + LSTM + (pred) head. grid N1*16 = 512,
// block 128 (2 waves). Block = (agent n, 8 batch rows). Wave 0: x@Wih,
// wave 1: h@Whh (no intra-block weight duplication). Lane: 8 interleaved cols.
__global__ __launch_bounds__(128, 1) void k_proj_lstm(
        const float* __restrict__ ao, const float* __restrict__ kvbuf,
        const float* __restrict__ wo_t,
        const float* __restrict__ ln_ego_g, const float* __restrict__ ln_ego_b,
        const float* __restrict__ ln_g, const float* __restrict__ ln_b,
        const float* __restrict__ ego_wih_t, const float* __restrict__ ego_whh_t,
        const float* __restrict__ veh_wih_t, const float* __restrict__ veh_whh_t,
        const float* __restrict__ bsum_all,
        const float* __restrict__ h_in, const float* __restrict__ c_in,
        float* __restrict__ h_out, float* __restrict__ c_out,
        const float* __restrict__ out_ego_w, const float* __restrict__ out_ego_b,
        const float* __restrict__ out_w, const float* __restrict__ out_b,
        float* __restrict__ pred_pos, float* __restrict__ out,
        int mode, int step) {
    int n = blockIdx.x >> 4, bg = blockIdx.x & 15;
    int b0 = bg * 8;
    int tid = threadIdx.x; // 128
    int w = tid >> 6, j = tid & 63;
    __shared__ float as_[8][F];        // 4 KB   attention output
    __shared__ float xh[2][8][F];      // 8 KB   [0]=LN-out x, [1]=h_in
    __shared__ float gacc[2][8][G4];   // 32 KB  partial gates
    __shared__ float h2s[8][F];        // 4 KB
    __shared__ float os[8][P6];
    for (int i = tid; i < 8 * (F / 4); i += 128) {
        int r = i >> 5, c4 = (i & 31) * 4;
        size_t bn = (size_t)(b0 + r) * N1 + n;
        *(float4*)&as_[r][c4]   = *(const float4*)(ao   + bn * F + c4);
        *(float4*)&xh[1][r][c4] = *(const float4*)(h_in + bn * F + c4);
    }
    __syncthreads();
    // ---- out-proj + residual + LN: wave w rows 4w..4w+3, lane j cols j, j+64
    {
        int r0 = w * 4;
        float a0[4] = {0, 0, 0, 0}, a1[4] = {0, 0, 0, 0};
        for (int k4 = 0; k4 < F; k4 += 4) {
            float4 w0 = *(const float4*)(wo_t + (size_t)j * F + k4);
            float4 w1 = *(const float4*)(wo_t + (size_t)(j + 64) * F + k4);
#pragma unroll
            for (int r = 0; r < 4; ++r) {
                float4 av = *(const float4*)&as_[r0 + r][k4];
                a0[r] += dot4(av, w0); a1[r] += dot4(av, w1);
            }
        }
        const float* gg  = (n == 0) ? ln_ego_g : ln_g;
        const float* bbv = (n == 0) ? ln_ego_b : ln_b;
        float g0 = gg[j], g1 = gg[j + 64], bb0 = bbv[j], bb1 = bbv[j + 64];
#pragma unroll
        for (int r = 0; r < 4; ++r) {
            int b = b0 + r0 + r;
            size_t base = ((size_t)b * KVN + n) * F;
            float x0 = kvbuf[base + j] + a0[r];
            float x1 = kvbuf[base + j + 64] + a1[r];
            float s1 = x0 + x1, s2 = x0 * x0 + x1 * x1;
#pragma unroll
            for (int off = 32; off > 0; off >>= 1) {
                s1 += __shfl_xor(s1, off, 64);
                s2 += __shfl_xor(s2, off, 64);
            }
            float mean = s1 * (1.f / F);
            float var = s2 * (1.f / F) - mean * mean;
            float rstd = rsqrtf(var + 1e-5f);
            xh[0][r0 + r][j]      = (x0 - mean) * rstd * g0 + bb0;
            xh[0][r0 + r][j + 64] = (x1 - mean) * rstd * g1 + bb1;
        }
    }
    __syncthreads();
    // ---- LSTM gate GEMM. lane j owns interleaved cols 8j..8j+7.
    const float* W = (n == 0) ? (w == 0 ? ego_wih_t : ego_whh_t)
                              : (w == 0 ? veh_wih_t : veh_whh_t);
    const float* Wp = W + 8 * j;
    const float (*xsrc)[F] = xh[w];
    float acc[8][8];
    if (w == 0) {
        const float* bsum = bsum_all + (n == 0 ? 0 : G4);
        float4 bv0 = *(const float4*)(bsum + 8 * j);
        float4 bv1 = *(const float4*)(bsum + 8 * j + 4);
#pragma unroll
        for (int r = 0; r < 8; ++r) {
            acc[r][0] = bv0.x; acc[r][1] = bv0.y; acc[r][2] = bv0.z; acc[r][3] = bv0.w;
            acc[r][4] = bv1.x; acc[r][5] = bv1.y; acc[r][6] = bv1.z; acc[r][7] = bv1.w;
        }
    } else {
#pragma unroll
        for (int r = 0; r < 8; ++r)
#pragma unroll
            for (int q = 0; q < 8; ++q) acc[r][q] = 0.f;
    }
    float4 wc[8], wn[8];
#pragma unroll
    for (int kk = 0; kk < 4; ++kk) {
        wc[kk * 2]     = *(const float4*)(Wp + (size_t)kk * G4);
        wc[kk * 2 + 1] = *(const float4*)(Wp + (size_t)kk * G4 + 4);
    }
    for (int k8 = 0; k8 < F; k8 += 8) {
#pragma unroll
        for (int kk = 0; kk < 4; ++kk) {
            wn[kk * 2]     = *(const float4*)(Wp + (size_t)(k8 + 4 + kk) * G4);
            wn[kk * 2 + 1] = *(const float4*)(Wp + (size_t)(k8 + 4 + kk) * G4 + 4);
        }
        lstm_fma4(xsrc, k8, wc, acc);
        if (k8 + 8 < F) {
#pragma unroll
            for (int kk = 0; kk < 4; ++kk) {
                wc[kk * 2]     = *(const float4*)(Wp + (size_t)(k8 + 8 + kk) * G4);
                wc[kk * 2 + 1] = *(const float4*)(Wp + (size_t)(k8 + 8 + kk) * G4 + 4);
            }
        }
        lstm_fma4(xsrc, k8 + 4, wn, acc);
    }
    // stash partial gates
#pragma unroll
    for (int r = 0; r < 8; ++r) {
        *(float4*)&gacc[w][r][8 * j]     = make_float4(acc[r][0], acc[r][1], acc[r][2], acc[r][3]);
        *(float4*)&gacc[w][r][8 * j + 4] = make_float4(acc[r][4], acc[r][5], acc[r][6], acc[r][7]);
    }
    __syncthreads();
    // gate finalize: thread tid -> feature tid, loop rows
#pragma unroll
    for (int r = 0; r < 8; ++r) {
        float4 gx = *(const float4*)&gacc[0][r][4 * tid];
        float4 gh = *(const float4*)&gacc[1][r][4 * tid];
        float ig = gx.x + gh.x, fg = gx.y + gh.y, gg = gx.z + gh.z, og = gx.w + gh.w;
        size_t bn = (size_t)(b0 + r) * N1 + n;
        float cold = c_in[bn * F + tid];
        float c2 = sigmoidf(fg) * cold + sigmoidf(ig) * tanhf(gg);
        float h2 = sigmoidf(og) * tanhf(c2);
        c_out[bn * F + tid] = c2;
        h_out[bn * F + tid] = h2;
        h2s[r][tid] = h2;
    }
    if (mode == 1) {
        const float* Wo = (n == 0) ? out_ego_w : out_w;
        const float* bb = (n == 0) ? out_ego_b : out_b;
        __syncthreads();
        for (int i = tid; i < 8 * P6; i += 128) {
            int r = i / P6, jo = i % P6;
            float a = bb[jo];
            for (int k4 = 0; k4 < F; k4 += 4) {
                float4 hx = *(const float4*)&h2s[r][k4];
                a += hx.x * Wo[(k4    ) * P6 + jo] + hx.y * Wo[(k4 + 1) * P6 + jo]
                   + hx.z * Wo[(k4 + 2) * P6 + jo] + hx.w * Wo[(k4 + 3) * P6 + jo];
            }
            os[r][jo] = a;
        }
        __syncthreads();
        if (tid < 8 * NP) {
            int r = tid / NP, p = tid % NP;
            size_t bn = (size_t)(b0 + r) * N1 + n;
            float dl = os[r][p * 6 + 0], yaw = os[r][p * 6 + 1];
            float* pp = pred_pos + (bn * NP + p) * 2;
            float px = pp[0] + dl * cosf(yaw);
            float py = pp[1] + dl * sinf(yaw);
            pp[0] = px; pp[1] = py;
            float* y = out + (size_t)step * B * N1 * P6 + (bn * NP + p) * 6;
            y[0] = px; y[1] = py;
            y[2] = os[r][p * 6 + 2]; y[3] = os[r][p * 6 + 3];
            y[4] = os[r][p * 6 + 4]; y[5] = os[r][p * 6 + 5];
        }
    }
}

// ---------------- launcher ----------------
extern "C" void kernel_launch(void* const* d_in, const int* in_sizes, int n_in,
                              void* d_out, int out_size, void* d_ws, size_t ws_size,
                              hipStream_t stream) {
    const float* input      = (const float*)d_in[0];
    const float* init_pos   = (const float*)d_in[1];
    const float* lane_input = (const float*)d_in[2];
    const float* mask_input = (const float*)d_in[3];
    const float* lane_mask  = (const float*)d_in[4];
    const float* conv_w     = (const float*)d_in[5];
    const float* conv_b     = (const float*)d_in[6];
    const float* pos_w      = (const float*)d_in[7];
    const float* pos_b      = (const float*)d_in[8];
    const float* lane_w1    = (const float*)d_in[9];
    const float* lane_b1    = (const float*)d_in[10];
    const float* lane_w2    = (const float*)d_in[11];
    const float* lane_b2    = (const float*)d_in[12];
    const float* lane_to_f  = (const float*)d_in[13];
    const float* wq         = (const float*)d_in[14];
    const float* wk         = (const float*)d_in[15];
    const float* wv         = (const float*)d_in[16];
    const float* wo         = (const float*)d_in[17];
    const float* ln_ego_g   = (const float*)d_in[18];
    const float* ln_ego_b   = (const float*)d_in[19];
    const float* ln_g       = (const float*)d_in[20];
    const float* ln_b       = (const float*)d_in[21];
    const float* ego_wih    = (const float*)d_in[22];
    const float* ego_whh    = (const float*)d_in[23];
    const float* ego_bih    = (const float*)d_in[24];
    const float* ego_bhh    = (const float*)d_in[25];
    const float* veh_wih    = (const float*)d_in[26];
    const float* veh_whh    = (const float*)d_in[27];
    const float* veh_bih    = (const float*)d_in[28];
    const float* veh_bhh    = (const float*)d_in[29];
    const float* out_ego_w  = (const float*)d_in[30];
    const float* out_ego_b  = (const float*)d_in[31];
    const float* out_w      = (const float*)d_in[32];
    const float* out_b      = (const float*)d_in[33];

    float* out = (float*)d_out;
    float* ws = (float*)d_ws;

    // workspace layout (floats)
    float* kv       = ws;                        // B*KVN*F
    float* qb       = kv + (size_t)B * KVN * F;  // B*N1*F
    float* kb       = qb + (size_t)B * N1 * F;   // B*KVN*F
    float* vb       = kb + (size_t)B * KVN * F;  // B*KVN*F
    float* ao       = vb + (size_t)B * KVN * F;  // B*N1*F
    float* h0       = ao + (size_t)B * N1 * F;
    float* h1p      = h0 + (size_t)B * N1 * F;
    float* c0       = h1p + (size_t)B * N1 * F;
    float* c1p      = c0 + (size_t)B * N1 * F;
    float* hist_pos = c1p + (size_t)B * N1 * F;             // HH*B*N1*2
    float* pred_pos = hist_pos + (size_t)HH * B * N1 * 2;   // B*N1*NP*2
    float* wqkvo_t  = pred_pos + (size_t)B * N1 * NP * 2;   // 4 * F*F
    float* wq_t = wqkvo_t;
    float* wk_t = wqkvo_t + (size_t)F * F;
    float* wv_t = wqkvo_t + (size_t)2 * F * F;
    float* wo_t = wqkvo_t + (size_t)3 * F * F;
    float* wlstm_t  = wqkvo_t + (size_t)4 * F * F;          // 4 * G4*F
    float* ego_wih_t = wlstm_t;
    float* ego_whh_t = wlstm_t + (size_t)G4 * F;
    float* veh_wih_t = wlstm_t + (size_t)2 * G4 * F;
    float* veh_whh_t = wlstm_t + (size_t)3 * G4 * F;
    float* bsum_all  = wlstm_t + (size_t)4 * G4 * F;        // 2 * G4

    float* hb[2] = {h0, h1p};
    float* cb[2] = {c0, c1p};

    // ---- init ----
    hipMemsetAsync(h0, 0, (size_t)B * N1 * F * sizeof(float), stream);
    hipMemsetAsync(c0, 0, (size_t)B * N1 * F * sizeof(float), stream);
    k_transpose4<<<4 * F, F, 0, stream>>>(wq, wk, wv, wo, wqkvo_t);
    k_transpose_lstm<<<4 * F, F, 0, stream>>>(ego_wih, ego_whh, veh_wih, veh_whh, wlstm_t);
    k_prep_bias<<<2, G4, 0, stream>>>(ego_bih, ego_bhh, veh_bih, veh_bhh, bsum_all);
    k_lane_tok<<<B * L, 64, 0, stream>>>(lane_input, lane_w1, lane_b1, lane_w2, lane_b2,
                                         lane_to_f, kv);
    k_hist_pos<<<(B * N1 + 255) / 256, 256, 0, stream>>>(input, init_pos, hist_pos, pred_pos);
    k_lane_kv<<<B * 8, 256, 0, stream>>>(kv, wk_t, wv_t, kb, vb);

    int cur = 0;
    for (int step = 0; step < HH + LEN; ++step) {
        int mode = (step < HH) ? 0 : 1;
        int t = (mode == 0) ? step : 0;
        int s = (mode == 0) ? 0 : step - HH;
        k_tok_qkv<<<B * 4, 256, 0, stream>>>(input, hist_pos, hb[cur], pred_pos,
                                             conv_w, conv_b, pos_w, pos_b,
                                             wq_t, wk_t, wv_t, kv, qb, kb, vb, mode, t);
        k_attn<<<B * 2, 256, 0, stream>>>(qb, kb, vb, mask_input, lane_mask, ao);
        k_proj_lstm<<<N1 * 16, 128, 0, stream>>>(ao, kv, wo_t,
                                                 ln_ego_g, ln_ego_b, ln_g, ln_b,
                                                 ego_wih_t, ego_whh_t, veh_wih_t, veh_whh_t,
                                                 bsum_all,
                                                 hb[cur], cb[cur], hb[1 - cur], cb[1 - cur],
                                                 out_ego_w, out_ego_b, out_w, out_b,
                                                 pred_pos, out, mode, s);
        cur ^= 1;
    }
}